// Round 16
// baseline (181.868 us; speedup 1.0000x reference)
//
#include <hip/hip_runtime.h>
#include <hip/hip_bf16.h>
#include <math.h>

#define LN2F 0.6931471805599453f
#define SCL 9.765625e-4f       // 1/1024
#define TWO_OVER_LN2 2.885390081777927f

typedef __attribute__((ext_vector_type(2))) float f32x2;

// ---------------------------------------------------------------------------
// Circulant trick: y[b, j*1024+i] = sum_k x[b,k] W[(i+k)%1024, j] is circular
// cross-correlation -> y_row = IDFT( Wf_j * conj(X_b) ), length-1024.
// Order irrelevant under sum(logcosh): radix-4 DIF forward + adjoint radix-4
// DIT inverse, no bit reversal. 2 real outputs per complex IFFT.
// k_corr (r16): 256 thr / 4 waves, wave owns TWO packed IFFT passes with
// disjoint padded LDS buffers. The two passes are MANUALLY INTERLEAVED at
// PW/BFLY granularity with disjoint register sets (r15 showed the compiler
// serializes them to save VGPRs: 88 VGPRs, issue = 1/6.1cy = bare serial
// chain). Alternating independent chains covers the ~6cy pk-op latency.
// Padded LDS (phys = s + s>>4), base+imm addressing, conflict-free.
// Complex math = VOP3P inline asm (v_pk_mul/fma/add with op_sel/neg; note
// v_pk_max_f32 does not exist on gfx950). logcosh in log2 domain, one log2
// per pair. 2/ln2 folded into Wfs scale + bias. Zero per-thread arrays.
// ---------------------------------------------------------------------------

#define LSW(s) ((s) ^ (((s) >> 4) & 15))   // (used by k_fft_fwd only)

__device__ __forceinline__ f32x2 mk2(float x, float y) { f32x2 r; r.x = x; r.y = y; return r; }

// ---- C complex helpers (forward-FFT kernel only) ----
__device__ __forceinline__ f32x2 cmul(f32x2 a, f32x2 b) {
  return a.xx * b + mk2(-a.y, a.y) * b.yx;
}

// ---- VOP3P packed helpers (k_corr) ----
__device__ __forceinline__ f32x2 pk_cmul(f32x2 a, f32x2 b) {   // a*b
  f32x2 d, t;
  asm("v_pk_mul_f32 %1, %2, %3 op_sel:[0,0] op_sel_hi:[0,1]\n\t"
      "v_pk_fma_f32 %0, %2, %3, %1 op_sel:[1,1,0] op_sel_hi:[1,0,1] neg_lo:[1,0,0]"
      : "=v"(d), "=&v"(t) : "v"(a), "v"(b));
  return d;
}
__device__ __forceinline__ f32x2 pk_cmulj(f32x2 a, f32x2 b) {  // a*conj(b)
  f32x2 d, t;
  asm("v_pk_mul_f32 %1, %2, %3 op_sel:[0,0] op_sel_hi:[0,1] neg_hi:[0,1]\n\t"
      "v_pk_fma_f32 %0, %2, %3, %1 op_sel:[1,1,0] op_sel_hi:[1,0,1]"
      : "=v"(d), "=&v"(t) : "v"(a), "v"(b));
  return d;
}
__device__ __forceinline__ f32x2 pk_add(f32x2 a, f32x2 b) {
  f32x2 o;
  asm("v_pk_add_f32 %0, %1, %2" : "=v"(o) : "v"(a), "v"(b));
  return o;
}
__device__ __forceinline__ f32x2 pk_sub(f32x2 a, f32x2 b) {
  f32x2 o;
  asm("v_pk_add_f32 %0, %1, %2 neg_lo:[0,1] neg_hi:[0,1]" : "=v"(o) : "v"(a), "v"(b));
  return o;
}
__device__ __forceinline__ f32x2 pk_addrot_p(f32x2 a, f32x2 d) {  // a + i*d
  f32x2 o;
  asm("v_pk_add_f32 %0, %1, %2 op_sel:[0,1] op_sel_hi:[1,0] neg_lo:[0,1]"
      : "=v"(o) : "v"(a), "v"(d));
  return o;
}
__device__ __forceinline__ f32x2 pk_addrot_m(f32x2 a, f32x2 d) {  // a - i*d
  f32x2 o;
  asm("v_pk_add_f32 %0, %1, %2 op_sel:[0,1] op_sel_hi:[1,0] neg_hi:[0,1]"
      : "=v"(o) : "v"(a), "v"(d));
  return o;
}
__device__ __forceinline__ f32x2 pk_nabs(f32x2 a) {  // |a| elementwise
  return mk2(fabsf(a.x), fabsf(a.y));
}

__device__ __forceinline__ float fast_exp2(float x) {
#if __has_builtin(__builtin_amdgcn_exp2f)
  return __builtin_amdgcn_exp2f(x);
#else
  return exp2f(x);
#endif
}
__device__ __forceinline__ float fast_log2(float x) {
#if __has_builtin(__builtin_amdgcn_logf)
  return __builtin_amdgcn_logf(x);
#else
  return __log2f(x);
#endif
}

// TWF[m] = e^{-2*pi*i*m/1024} for the compile-time m we need
__device__ __forceinline__ f32x2 Ctw(int m) {
  switch (m) {
    case 0:   return mk2(1.f, 0.f);
    case 1:   return mk2(0.999981175f, -0.006135885f);
    case 2:   return mk2(0.999924702f, -0.012271538f);
    case 3:   return mk2(0.999830582f, -0.018406730f);
    case 64:  return mk2(0.923879533f, -0.382683432f);
    case 128: return mk2(0.707106781f, -0.707106781f);
    case 192: return mk2(0.382683432f, -0.923879533f);
    case 256: return mk2(0.f, -1.f);
    case 384: return mk2(-0.707106781f, -0.707106781f);
    case 576: return mk2(-0.923879533f, 0.382683432f);
  }
  return mk2(1.f, 0.f);
}

// forward DIF butterfly (output twiddles, e^{-}) -- C math, fwd kernel only
#define BFLY_F(x0,x1,x2,x3,W1,W2,W3,y0,y1,y2,y3) do { \
  f32x2 t0 = x0+x2, t1 = x1+x3, t2 = x0-x2, d_ = x1-x3; \
  f32x2 t3 = mk2(d_.y, -d_.x); \
  y0 = t0+t1; y1 = cmul(t2+t3, W1); \
  y2 = cmul(t0-t1, W2); y3 = cmul(t2-t3, W3); } while(0)

// inverse DIT butterfly (input conj-twiddles, e^{+}) -- packed asm
#define BFLY_I(x0,x1,x2,x3,W1,W2,W3,y0,y1,y2,y3) do { \
  f32x2 u1 = pk_cmulj(x1,W1), u2 = pk_cmulj(x2,W2), u3 = pk_cmulj(x3,W3); \
  f32x2 t0 = pk_add(x0,u2), t1 = pk_add(u1,u3), t2 = pk_sub(x0,u2), d_ = pk_sub(u1,u3); \
  y0 = pk_add(t0,t1); y1 = pk_addrot_p(t2,d_); \
  y2 = pk_sub(t0,t1); y3 = pk_addrot_m(t2,d_); } while(0)

#define BFLY_I1(x0,x1,x2,x3,y0,y1,y2,y3) do { \
  f32x2 t0 = pk_add(x0,x2), t1 = pk_add(x1,x3), t2 = pk_sub(x0,x2), d_ = pk_sub(x1,x3); \
  y0 = pk_add(t0,t1); y1 = pk_addrot_p(t2,d_); \
  y2 = pk_sub(t0,t1); y3 = pk_addrot_m(t2,d_); } while(0)

__global__ void k_twiddle(f32x2* __restrict__ tw) {
  int m = blockIdx.x * 256 + threadIdx.x;
  float th = (float)(2.0 * M_PI / 1024.0) * (float)m;
  tw[m] = mk2(cosf(th), -sinf(th));
}

// Forward FFT-1024 (radix-4 DIF). One wave per row, 4 rows/block. Real input.
// dst values are multiplied by `scale`.
__global__ __launch_bounds__(256, 3) void k_fft_fwd(
    const float* __restrict__ src, int estride, int rstride,
    const f32x2* __restrict__ tw, f32x2* __restrict__ dst, float scale,
    const float* __restrict__ vbias, float* __restrict__ out, int dorow) {
  __shared__ __align__(16) f32x2 fft[4][1024];
  int tid = threadIdx.x, wv = tid >> 6, u = tid & 63;
  int row = blockIdx.x * 4 + wv;
  const float* xr = src + (size_t)row * rstride;
  f32x2* L = fft[wv];
  f32x2 twu = tw[u];
  f32x2 tw4u = tw[4 * u];
  int tp = u & 3;
  f32x2 tw16t = tw[16 * tp], tw64t = tw[64 * tp];

  float vr[4][4]; float rs = 0.f;
  #pragma unroll
  for (int a = 0; a < 4; ++a)
    #pragma unroll
    for (int k = 0; k < 4; ++k) {
      float s = xr[(u + 64 * a + 256 * k) * estride];
      vr[a][k] = s; rs += s;
    }
  f32x2 v[4][4];
  #pragma unroll
  for (int a = 0; a < 4; ++a) {
    float x0 = vr[a][0], x1 = vr[a][1], x2 = vr[a][2], x3 = vr[a][3];
    float t0 = x0 + x2, t1 = x1 + x3, t2 = x0 - x2, dm = x1 - x3;
    f32x2 W1 = cmul(twu, Ctw(64 * a));
    f32x2 W2 = cmul(W1, W1), W3 = cmul(W1, W2);
    v[a][0] = mk2(t0 + t1, 0.f);
    v[a][1] = cmul(mk2(t2, -dm), W1);
    v[a][2] = cmul(mk2(t0 - t1, 0.f), W2);
    v[a][3] = cmul(mk2(t2, dm), W3);
  }
  {
    f32x2 W1 = tw4u, W2 = cmul(W1, W1), W3 = cmul(W1, W2);
    #pragma unroll
    for (int k = 0; k < 4; ++k) {
      f32x2 y0,y1,y2,y3;
      BFLY_F(v[0][k], v[1][k], v[2][k], v[3][k], W1, W2, W3, y0,y1,y2,y3);
      v[0][k]=y0; v[1][k]=y1; v[2][k]=y2; v[3][k]=y3;
    }
  }
  #pragma unroll
  for (int a = 0; a < 4; ++a)
    #pragma unroll
    for (int k = 0; k < 4; ++k)
      L[LSW(u + 64 * a + 256 * k)] = v[a][k];

  int D = u >> 2;
  f32x2 w[4][4];
  #pragma unroll
  for (int c = 0; c < 4; ++c)
    #pragma unroll
    for (int ap = 0; ap < 4; ++ap)
      w[c][ap] = L[LSW(64 * D + 16 * c + 4 * ap + tp)];
  #pragma unroll
  for (int ap = 0; ap < 4; ++ap) {
    f32x2 W1 = cmul(Ctw(64 * ap), tw16t);
    f32x2 W2 = cmul(W1, W1), W3 = cmul(W1, W2);
    f32x2 y0,y1,y2,y3;
    BFLY_F(w[0][ap], w[1][ap], w[2][ap], w[3][ap], W1, W2, W3, y0,y1,y2,y3);
    w[0][ap]=y0; w[1][ap]=y1; w[2][ap]=y2; w[3][ap]=y3;
  }
  {
    f32x2 W1 = tw64t, W2 = cmul(W1, W1), W3 = cmul(W1, W2);
    #pragma unroll
    for (int c = 0; c < 4; ++c) {
      f32x2 y0,y1,y2,y3;
      BFLY_F(w[c][0], w[c][1], w[c][2], w[c][3], W1, W2, W3, y0,y1,y2,y3);
      w[c][0]=y0; w[c][1]=y1; w[c][2]=y2; w[c][3]=y3;
    }
  }
  #pragma unroll
  for (int c = 0; c < 4; ++c)
    #pragma unroll
    for (int ap = 0; ap < 4; ++ap)
      L[LSW(64 * D + 16 * c + 4 * ap + tp)] = w[c][ap];

  f32x2* drow = dst + (size_t)row * 1024;
  #pragma unroll
  for (int j = 0; j < 4; ++j) {
    f32x2 z0 = L[LSW(16 * u + 4 * j)];
    f32x2 z1 = L[LSW(16 * u + 4 * j + 1)];
    f32x2 z2 = L[LSW(16 * u + 4 * j + 2)];
    f32x2 z3 = L[LSW(16 * u + 4 * j + 3)];
    f32x2 t0 = z0+z2, t1 = z1+z3, t2 = z0-z2, d = z1-z3;
    f32x2 t3 = mk2(d.y, -d.x);
    f32x2 y0 = (t0+t1)*scale, y1 = (t2+t3)*scale, y2 = (t0-t1)*scale, y3 = (t2-t3)*scale;
    float4* dp = (float4*)(drow + 16 * u + 4 * j);
    dp[0] = make_float4(y0.x, y0.y, y1.x, y1.y);
    dp[1] = make_float4(y2.x, y2.y, y3.x, y3.y);
  }
  if (dorow) {
    #pragma unroll
    for (int m = 32; m; m >>= 1) rs += __shfl_down(rs, m);
    if (u == 0) out[row] = vbias[0] * rs;
  }
}

// ---- k_corr: interleaved two-pass macros (disjoint regs, alternating ops) ----

#define PWp(WP0, WP1, M, XA, XB, ZA, ZB) do { \
  float4 qa_ = (WP0)[M], qb_ = (WP1)[M]; \
  f32x2 g1_ = pk_cmulj(mk2(qa_.x,qa_.y), XA); \
  f32x2 g2_ = pk_cmulj(mk2(qb_.x,qb_.y), XA); \
  ZA = pk_addrot_p(g1_, g2_); \
  g1_ = pk_cmulj(mk2(qa_.z,qa_.w), XB); \
  g2_ = pk_cmulj(mk2(qb_.z,qb_.w), XB); \
  ZB = pk_addrot_p(g1_, g2_); } while(0)

// log2-domain logcosh: u already = |v+b|*2/ln2; one log2 per element pair
#define LCACC(C, B2, ACCL, ACCU) do { \
  f32x2 t2_ = pk_add((C), (B2)); \
  f32x2 u2_ = pk_nabs(t2_); \
  float p_ = (1.f + fast_exp2(-u2_.x)) * (1.f + fast_exp2(-u2_.y)); \
  ACCL += fast_log2(p_); \
  ACCU = pk_add(ACCU, u2_); } while(0)

// 256 thr = 4 waves; wave wv owns j-pairs (4wv,4wv+1) [pass a] and
// (4wv+2,4wv+3) [pass b], manually interleaved phase-by-phase.
__global__ __launch_bounds__(256, 2) void k_corr(
    const f32x2* __restrict__ X, const f32x2* __restrict__ Wfs,
    const float* __restrict__ bs, const f32x2* __restrict__ tw,
    float* __restrict__ out) {
  __shared__ __align__(16) f32x2 LBW[4][2][1088];   // [wave][pass][slot]
  __shared__ float red[4];
  int tid = threadIdx.x, wv = tid >> 6, u = tid & 63;
  int b = blockIdx.x;
  f32x2* L0 = LBW[wv][0];
  f32x2* L1 = LBW[wv][1];
  f32x2* LPA0 = L0 + 17 * u;
  f32x2* LPA1 = L1 + 17 * u;
  f32x2* LPB0 = L0 + 272 * (u >> 4) + (u & 15);
  f32x2* LPB1 = L1 + 272 * (u >> 4) + (u & 15);
  f32x2* LPC0 = L0 + 4 * u + (u >> 2);
  f32x2* LPC1 = L1 + 4 * u + (u >> 2);
  f32x2 tw4u = tw[4 * u];
  int t = u & 15;
  f32x2 tw16t = tw[16 * t], tw4t = tw[4 * t];
  int s16 = 16 * u;

  f32x2 xr0,xr1,xr2,xr3,xr4,xr5,xr6,xr7,xr8,xr9,xr10,xr11,xr12,xr13,xr14,xr15;
  {
    const float4* Xp = (const float4*)(X + (size_t)b * 1024 + s16);
    float4 q;
    q = Xp[0]; xr0  = mk2(q.x,q.y); xr1  = mk2(q.z,q.w);
    q = Xp[1]; xr2  = mk2(q.x,q.y); xr3  = mk2(q.z,q.w);
    q = Xp[2]; xr4  = mk2(q.x,q.y); xr5  = mk2(q.z,q.w);
    q = Xp[3]; xr6  = mk2(q.x,q.y); xr7  = mk2(q.z,q.w);
    q = Xp[4]; xr8  = mk2(q.x,q.y); xr9  = mk2(q.z,q.w);
    q = Xp[5]; xr10 = mk2(q.x,q.y); xr11 = mk2(q.z,q.w);
    q = Xp[6]; xr12 = mk2(q.x,q.y); xr13 = mk2(q.z,q.w);
    q = Xp[7]; xr14 = mk2(q.x,q.y); xr15 = mk2(q.z,q.w);
  }
  f32x2 bias2a = mk2(bs[4*wv]   * TWO_OVER_LN2, bs[4*wv+1] * TWO_OVER_LN2);
  f32x2 bias2b = mk2(bs[4*wv+2] * TWO_OVER_LN2, bs[4*wv+3] * TWO_OVER_LN2);

  const float4* W0pa = (const float4*)(Wfs + (size_t)(4*wv)     * 1024 + s16);
  const float4* W1pa = (const float4*)(Wfs + (size_t)(4*wv + 1) * 1024 + s16);
  const float4* W0pb = (const float4*)(Wfs + (size_t)(4*wv + 2) * 1024 + s16);
  const float4* W1pb = (const float4*)(Wfs + (size_t)(4*wv + 3) * 1024 + s16);

  // ---- phase A (both passes, op-interleaved): pointwise + s0 + s1 + write
  {
    f32x2 za0,za1,za2,za3,za4,za5,za6,za7,za8,za9,za10,za11,za12,za13,za14,za15;
    f32x2 zb0,zb1,zb2,zb3,zb4,zb5,zb6,zb7,zb8,zb9,zb10,zb11,zb12,zb13,zb14,zb15;
    PWp(W0pa,W1pa,0, xr0,xr1,  za0,za1);   PWp(W0pb,W1pb,0, xr0,xr1,  zb0,zb1);
    PWp(W0pa,W1pa,1, xr2,xr3,  za2,za3);   PWp(W0pb,W1pb,1, xr2,xr3,  zb2,zb3);
    PWp(W0pa,W1pa,2, xr4,xr5,  za4,za5);   PWp(W0pb,W1pb,2, xr4,xr5,  zb4,zb5);
    PWp(W0pa,W1pa,3, xr6,xr7,  za6,za7);   PWp(W0pb,W1pb,3, xr6,xr7,  zb6,zb7);
    PWp(W0pa,W1pa,4, xr8,xr9,  za8,za9);   PWp(W0pb,W1pb,4, xr8,xr9,  zb8,zb9);
    PWp(W0pa,W1pa,5, xr10,xr11,za10,za11); PWp(W0pb,W1pb,5, xr10,xr11,zb10,zb11);
    PWp(W0pa,W1pa,6, xr12,xr13,za12,za13); PWp(W0pb,W1pb,6, xr12,xr13,zb12,zb13);
    PWp(W0pa,W1pa,7, xr14,xr15,za14,za15); PWp(W0pb,W1pb,7, xr14,xr15,zb14,zb15);
    // s0
    BFLY_I1(za0,za1,za2,za3,     za0,za1,za2,za3);
    BFLY_I1(zb0,zb1,zb2,zb3,     zb0,zb1,zb2,zb3);
    BFLY_I1(za4,za5,za6,za7,     za4,za5,za6,za7);
    BFLY_I1(zb4,zb5,zb6,zb7,     zb4,zb5,zb6,zb7);
    BFLY_I1(za8,za9,za10,za11,   za8,za9,za10,za11);
    BFLY_I1(zb8,zb9,zb10,zb11,   zb8,zb9,zb10,zb11);
    BFLY_I1(za12,za13,za14,za15, za12,za13,za14,za15);
    BFLY_I1(zb12,zb13,zb14,zb15, zb12,zb13,zb14,zb15);
    // s1
    BFLY_I1(za0,za4,za8,za12, za0,za4,za8,za12);
    BFLY_I1(zb0,zb4,zb8,zb12, zb0,zb4,zb8,zb12);
    BFLY_I(za1,za5,za9,za13, Ctw(64),Ctw(128),Ctw(192), za1,za5,za9,za13);
    BFLY_I(zb1,zb5,zb9,zb13, Ctw(64),Ctw(128),Ctw(192), zb1,zb5,zb9,zb13);
    BFLY_I(za2,za6,za10,za14, Ctw(128),Ctw(256),Ctw(384), za2,za6,za10,za14);
    BFLY_I(zb2,zb6,zb10,zb14, Ctw(128),Ctw(256),Ctw(384), zb2,zb6,zb10,zb14);
    BFLY_I(za3,za7,za11,za15, Ctw(192),Ctw(384),Ctw(576), za3,za7,za11,za15);
    BFLY_I(zb3,zb7,zb11,zb15, Ctw(192),Ctw(384),Ctw(576), zb3,zb7,zb11,zb15);
    LPA0[0]=za0;   LPA1[0]=zb0;   LPA0[1]=za1;   LPA1[1]=zb1;
    LPA0[2]=za2;   LPA1[2]=zb2;   LPA0[3]=za3;   LPA1[3]=zb3;
    LPA0[4]=za4;   LPA1[4]=zb4;   LPA0[5]=za5;   LPA1[5]=zb5;
    LPA0[6]=za6;   LPA1[6]=zb6;   LPA0[7]=za7;   LPA1[7]=zb7;
    LPA0[8]=za8;   LPA1[8]=zb8;   LPA0[9]=za9;   LPA1[9]=zb9;
    LPA0[10]=za10; LPA1[10]=zb10; LPA0[11]=za11; LPA1[11]=zb11;
    LPA0[12]=za12; LPA1[12]=zb12; LPA0[13]=za13; LPA1[13]=zb13;
    LPA0[14]=za14; LPA1[14]=zb14; LPA0[15]=za15; LPA1[15]=zb15;
  }

  // s2/s3 twiddles (shared by both passes)
  f32x2 TB1 = tw16t, TB2 = pk_cmul(TB1,TB1), TB3 = pk_cmul(TB1,TB2);
  f32x2 TC10 = tw4t,                  TC20 = pk_cmul(TC10,TC10), TC30 = pk_cmul(TC10,TC20);
  f32x2 TC11 = pk_cmul(tw4t,Ctw(64)),  TC21 = pk_cmul(TC11,TC11), TC31 = pk_cmul(TC11,TC21);
  f32x2 TC12 = pk_cmul(tw4t,Ctw(128)), TC22 = pk_cmul(TC12,TC12), TC32 = pk_cmul(TC12,TC22);
  f32x2 TC13 = pk_cmul(tw4t,Ctw(192)), TC23 = pk_cmul(TC13,TC13), TC33 = pk_cmul(TC13,TC23);

  // ---- phase B (both passes, op-interleaved): read + s2 + s3 + write
  {
    f32x2 wa00,wa01,wa02,wa03,wa10,wa11,wa12,wa13,wa20,wa21,wa22,wa23,wa30,wa31,wa32,wa33;
    f32x2 wb00,wb01,wb02,wb03,wb10,wb11,wb12,wb13,wb20,wb21,wb22,wb23,wb30,wb31,wb32,wb33;
    wa00 = LPB0[0];   wb00 = LPB1[0];   wa01 = LPB0[68];  wb01 = LPB1[68];
    wa02 = LPB0[136]; wb02 = LPB1[136]; wa03 = LPB0[204]; wb03 = LPB1[204];
    wa10 = LPB0[17];  wb10 = LPB1[17];  wa11 = LPB0[85];  wb11 = LPB1[85];
    wa12 = LPB0[153]; wb12 = LPB1[153]; wa13 = LPB0[221]; wb13 = LPB1[221];
    wa20 = LPB0[34];  wb20 = LPB1[34];  wa21 = LPB0[102]; wb21 = LPB1[102];
    wa22 = LPB0[170]; wb22 = LPB1[170]; wa23 = LPB0[238]; wb23 = LPB1[238];
    wa30 = LPB0[51];  wb30 = LPB1[51];  wa31 = LPB0[119]; wb31 = LPB1[119];
    wa32 = LPB0[187]; wb32 = LPB1[187]; wa33 = LPB0[255]; wb33 = LPB1[255];
    BFLY_I(wa00,wa10,wa20,wa30, TB1,TB2,TB3, wa00,wa10,wa20,wa30);
    BFLY_I(wb00,wb10,wb20,wb30, TB1,TB2,TB3, wb00,wb10,wb20,wb30);
    BFLY_I(wa01,wa11,wa21,wa31, TB1,TB2,TB3, wa01,wa11,wa21,wa31);
    BFLY_I(wb01,wb11,wb21,wb31, TB1,TB2,TB3, wb01,wb11,wb21,wb31);
    BFLY_I(wa02,wa12,wa22,wa32, TB1,TB2,TB3, wa02,wa12,wa22,wa32);
    BFLY_I(wb02,wb12,wb22,wb32, TB1,TB2,TB3, wb02,wb12,wb22,wb32);
    BFLY_I(wa03,wa13,wa23,wa33, TB1,TB2,TB3, wa03,wa13,wa23,wa33);
    BFLY_I(wb03,wb13,wb23,wb33, TB1,TB2,TB3, wb03,wb13,wb23,wb33);
    BFLY_I(wa00,wa01,wa02,wa03, TC10,TC20,TC30, wa00,wa01,wa02,wa03);
    BFLY_I(wb00,wb01,wb02,wb03, TC10,TC20,TC30, wb00,wb01,wb02,wb03);
    BFLY_I(wa10,wa11,wa12,wa13, TC11,TC21,TC31, wa10,wa11,wa12,wa13);
    BFLY_I(wb10,wb11,wb12,wb13, TC11,TC21,TC31, wb10,wb11,wb12,wb13);
    BFLY_I(wa20,wa21,wa22,wa23, TC12,TC22,TC32, wa20,wa21,wa22,wa23);
    BFLY_I(wb20,wb21,wb22,wb23, TC12,TC22,TC32, wb20,wb21,wb22,wb23);
    BFLY_I(wa30,wa31,wa32,wa33, TC13,TC23,TC33, wa30,wa31,wa32,wa33);
    BFLY_I(wb30,wb31,wb32,wb33, TC13,TC23,TC33, wb30,wb31,wb32,wb33);
    LPB0[0]=wa00;   LPB1[0]=wb00;   LPB0[68]=wa01;  LPB1[68]=wb01;
    LPB0[136]=wa02; LPB1[136]=wb02; LPB0[204]=wa03; LPB1[204]=wb03;
    LPB0[17]=wa10;  LPB1[17]=wb10;  LPB0[85]=wa11;  LPB1[85]=wb11;
    LPB0[153]=wa12; LPB1[153]=wb12; LPB0[221]=wa13; LPB1[221]=wb13;
    LPB0[34]=wa20;  LPB1[34]=wb20;  LPB0[102]=wa21; LPB1[102]=wb21;
    LPB0[170]=wa22; LPB1[170]=wb22; LPB0[238]=wa23; LPB1[238]=wb23;
    LPB0[51]=wa30;  LPB1[51]=wb30;  LPB0[119]=wa31; LPB1[119]=wb31;
    LPB0[187]=wa32; LPB1[187]=wb32; LPB0[255]=wa33; LPB1[255]=wb33;
  }

  // s4 twiddles (shared)
  f32x2 TD10 = tw4u,                 TD20 = pk_cmul(TD10,TD10), TD30 = pk_cmul(TD10,TD20);
  f32x2 TD11 = pk_cmul(tw4u,Ctw(1)), TD21 = pk_cmul(TD11,TD11), TD31 = pk_cmul(TD11,TD21);
  f32x2 TD12 = pk_cmul(tw4u,Ctw(2)), TD22 = pk_cmul(TD12,TD12), TD32 = pk_cmul(TD12,TD22);
  f32x2 TD13 = pk_cmul(tw4u,Ctw(3)), TD23 = pk_cmul(TD13,TD13), TD33 = pk_cmul(TD13,TD23);

  // ---- phase C (both passes, op-interleaved): read + s4 + logcosh
  float accLa = 0.f, accLb = 0.f;
  f32x2 accUa = mk2(0.f, 0.f), accUb = mk2(0.f, 0.f);
#define QPC_PAIR(I, T1, T2, T3) do { \
    f32x2 ca0 = LPC0[(I)],     cb0 = LPC1[(I)]; \
    f32x2 ca1 = LPC0[(I)+272], cb1 = LPC1[(I)+272]; \
    f32x2 ca2 = LPC0[(I)+544], cb2 = LPC1[(I)+544]; \
    f32x2 ca3 = LPC0[(I)+816], cb3 = LPC1[(I)+816]; \
    BFLY_I(ca0,ca1,ca2,ca3, T1,T2,T3, ca0,ca1,ca2,ca3); \
    BFLY_I(cb0,cb1,cb2,cb3, T1,T2,T3, cb0,cb1,cb2,cb3); \
    LCACC(ca0, bias2a, accLa, accUa); LCACC(cb0, bias2b, accLb, accUb); \
    LCACC(ca1, bias2a, accLa, accUa); LCACC(cb1, bias2b, accLb, accUb); \
    LCACC(ca2, bias2a, accLa, accUa); LCACC(cb2, bias2b, accLb, accUb); \
    LCACC(ca3, bias2a, accLa, accUa); LCACC(cb3, bias2b, accLb, accUb); \
  } while(0)
  QPC_PAIR(0, TD10, TD20, TD30);
  QPC_PAIR(1, TD11, TD21, TD31);
  QPC_PAIR(2, TD12, TD22, TD32);
  QPC_PAIR(3, TD13, TD23, TD33);
#undef QPC_PAIR

  float acc = (accLa + accLb)
            + 0.5f * ((accUa.x + accUa.y) + (accUb.x + accUb.y));
  #pragma unroll
  for (int m = 32; m; m >>= 1) acc += __shfl_down(acc, m);
  if (u == 0) red[wv] = acc;
  __syncthreads();
  if (tid == 0) {
    float s = (red[0] + red[1]) + (red[2] + red[3]);
    out[b] += LN2F * (s - 16384.f);
  }
}

// fallback if workspace is too small: correct but slow
__global__ void k_naive(const float* __restrict__ x, const float* __restrict__ W,
                        const float* __restrict__ bs, const float* __restrict__ vb,
                        float* __restrict__ out) {
  int b = blockIdx.x;
  __shared__ float xs[1024];
  __shared__ float red[256];
  int t = threadIdx.x;
  float xsum = 0.f;
  for (int i = t; i < 1024; i += 256) { float v = x[(size_t)b * 1024 + i]; xs[i] = v; xsum += v; }
  __syncthreads();
  float tot = vb[0] * xsum;
  for (int h = t; h < 16384; h += 256) {
    int j = h >> 10, kh = h & 1023;
    float a = bs[j];
    for (int i = 0; i < 1024; ++i) a += xs[i] * W[((i + kh) & 1023) * 16 + j];
    float ax = fabsf(a);
    tot += ax + __logf(1.f + __expf(-2.f * ax)) - LN2F;
  }
  red[t] = tot;
  __syncthreads();
  for (int s2 = 128; s2; s2 >>= 1) { if (t < s2) red[t] += red[t + s2]; __syncthreads(); }
  if (t == 0) out[b] = red[0];
}

extern "C" void kernel_launch(void* const* d_in, const int* in_sizes, int n_in,
                              void* d_out, int out_size, void* d_ws, size_t ws_size,
                              hipStream_t stream) {
  const float* x  = (const float*)d_in[0];   // [4096,1024]
  const float* W  = (const float*)d_in[1];   // [1024,16]
  const float* bs = (const float*)d_in[2];   // [16]
  const float* vb = (const float*)d_in[3];   // [1]
  float* out = (float*)d_out;                // [4096]

  size_t need = 8192 + 131072 + (size_t)4096 * 1024 * 8;  // tw + Wfs + X
  if (ws_size < need) {
    k_naive<<<4096, 256, 0, stream>>>(x, W, bs, vb, out);
    return;
  }
  f32x2* tw  = (f32x2*)d_ws;
  f32x2* Wfs = (f32x2*)((char*)d_ws + 8192);
  f32x2* X   = (f32x2*)((char*)d_ws + 8192 + 131072);

  k_twiddle<<<4, 256, 0, stream>>>(tw);
  // 16 W-column spectra scaled by (1/1024)*(2/ln2) -- folds IFFT norm + logcosh scale
  k_fft_fwd<<<4, 256, 0, stream>>>(W, 16, 1, tw, Wfs, SCL * TWO_OVER_LN2, vb, out, 0);
  // 4096 x-row spectra; also out[row] = vb * rowsum(x[row])
  k_fft_fwd<<<1024, 256, 0, stream>>>(x, 1, 1024, tw, X, 1.0f, vb, out, 1);
  k_corr<<<4096, 256, 0, stream>>>(X, Wfs, bs, tw, out);
}

// Round 17
// 129.307 us; speedup vs baseline: 1.4065x; 1.4065x over previous
//
#include <hip/hip_runtime.h>
#include <hip/hip_bf16.h>
#include <math.h>

#define LN2F 0.6931471805599453f
#define SCL 9.765625e-4f       // 1/1024
#define TWO_OVER_LN2 2.885390081777927f

typedef __attribute__((ext_vector_type(2))) float f32x2;

// ---------------------------------------------------------------------------
// Circulant trick: y[b, j*1024+i] = sum_k x[b,k] W[(i+k)%1024, j] is circular
// cross-correlation -> y_row = IDFT( Wf_j * conj(X_b) ), length-1024.
// Order irrelevant under sum(logcosh): radix-4 DIF forward + adjoint radix-4
// DIT inverse, no bit reversal. 2 real outputs per complex IFFT.
// k_corr (r15 structure, best measured): 256 thr / 4 waves, wave wv owns TWO
// packed IFFT passes (j 4wv..4wv+3) phase-pipelined A0 A1 | B0 B1 | C0 C1 on
// disjoint padded LDS buffers. (r16 tried op-level manual interleave of the
// two passes; the pre-RA scheduler reordered it away (VGPR stayed 88) and
// the resulting schedule was 1.5x WORSE -- reverted.)
// Padded LDS (phys = s + s>>4), base+imm addressing, conflict-free.
// Complex math = VOP3P inline asm (v_pk_mul/fma/add with op_sel/neg; note
// v_pk_max_f32 does not exist on gfx950). logcosh in log2 domain, one log2
// per pair. 2/ln2 folded into Wfs scale + bias. Zero per-thread arrays.
// ---------------------------------------------------------------------------

#define LSW(s) ((s) ^ (((s) >> 4) & 15))   // (used by k_fft_fwd only)

__device__ __forceinline__ f32x2 mk2(float x, float y) { f32x2 r; r.x = x; r.y = y; return r; }

// ---- C complex helpers (forward-FFT kernel only) ----
__device__ __forceinline__ f32x2 cmul(f32x2 a, f32x2 b) {
  return a.xx * b + mk2(-a.y, a.y) * b.yx;
}

// ---- VOP3P packed helpers (k_corr) ----
__device__ __forceinline__ f32x2 pk_cmul(f32x2 a, f32x2 b) {   // a*b
  f32x2 d, t;
  asm("v_pk_mul_f32 %1, %2, %3 op_sel:[0,0] op_sel_hi:[0,1]\n\t"
      "v_pk_fma_f32 %0, %2, %3, %1 op_sel:[1,1,0] op_sel_hi:[1,0,1] neg_lo:[1,0,0]"
      : "=v"(d), "=&v"(t) : "v"(a), "v"(b));
  return d;
}
__device__ __forceinline__ f32x2 pk_cmulj(f32x2 a, f32x2 b) {  // a*conj(b)
  f32x2 d, t;
  asm("v_pk_mul_f32 %1, %2, %3 op_sel:[0,0] op_sel_hi:[0,1] neg_hi:[0,1]\n\t"
      "v_pk_fma_f32 %0, %2, %3, %1 op_sel:[1,1,0] op_sel_hi:[1,0,1]"
      : "=v"(d), "=&v"(t) : "v"(a), "v"(b));
  return d;
}
__device__ __forceinline__ f32x2 pk_add(f32x2 a, f32x2 b) {
  f32x2 o;
  asm("v_pk_add_f32 %0, %1, %2" : "=v"(o) : "v"(a), "v"(b));
  return o;
}
__device__ __forceinline__ f32x2 pk_sub(f32x2 a, f32x2 b) {
  f32x2 o;
  asm("v_pk_add_f32 %0, %1, %2 neg_lo:[0,1] neg_hi:[0,1]" : "=v"(o) : "v"(a), "v"(b));
  return o;
}
__device__ __forceinline__ f32x2 pk_addrot_p(f32x2 a, f32x2 d) {  // a + i*d
  f32x2 o;
  asm("v_pk_add_f32 %0, %1, %2 op_sel:[0,1] op_sel_hi:[1,0] neg_lo:[0,1]"
      : "=v"(o) : "v"(a), "v"(d));
  return o;
}
__device__ __forceinline__ f32x2 pk_addrot_m(f32x2 a, f32x2 d) {  // a - i*d
  f32x2 o;
  asm("v_pk_add_f32 %0, %1, %2 op_sel:[0,1] op_sel_hi:[1,0] neg_hi:[0,1]"
      : "=v"(o) : "v"(a), "v"(d));
  return o;
}
__device__ __forceinline__ f32x2 pk_nabs(f32x2 a) {  // |a| elementwise
  // no v_pk_max_f32 on gfx950: per-half sign-bit clear (2x v_and_b32)
  return mk2(fabsf(a.x), fabsf(a.y));
}

__device__ __forceinline__ float fast_exp2(float x) {
#if __has_builtin(__builtin_amdgcn_exp2f)
  return __builtin_amdgcn_exp2f(x);
#else
  return exp2f(x);
#endif
}
__device__ __forceinline__ float fast_log2(float x) {
#if __has_builtin(__builtin_amdgcn_logf)
  return __builtin_amdgcn_logf(x);
#else
  return __log2f(x);
#endif
}

// TWF[m] = e^{-2*pi*i*m/1024} for the compile-time m we need
__device__ __forceinline__ f32x2 Ctw(int m) {
  switch (m) {
    case 0:   return mk2(1.f, 0.f);
    case 1:   return mk2(0.999981175f, -0.006135885f);
    case 2:   return mk2(0.999924702f, -0.012271538f);
    case 3:   return mk2(0.999830582f, -0.018406730f);
    case 64:  return mk2(0.923879533f, -0.382683432f);
    case 128: return mk2(0.707106781f, -0.707106781f);
    case 192: return mk2(0.382683432f, -0.923879533f);
    case 256: return mk2(0.f, -1.f);
    case 384: return mk2(-0.707106781f, -0.707106781f);
    case 576: return mk2(-0.923879533f, 0.382683432f);
  }
  return mk2(1.f, 0.f);
}

// forward DIF butterfly (output twiddles, e^{-}) -- C math, fwd kernel only
#define BFLY_F(x0,x1,x2,x3,W1,W2,W3,y0,y1,y2,y3) do { \
  f32x2 t0 = x0+x2, t1 = x1+x3, t2 = x0-x2, d_ = x1-x3; \
  f32x2 t3 = mk2(d_.y, -d_.x); \
  y0 = t0+t1; y1 = cmul(t2+t3, W1); \
  y2 = cmul(t0-t1, W2); y3 = cmul(t2-t3, W3); } while(0)

// inverse DIT butterfly (input conj-twiddles, e^{+}) -- packed asm
#define BFLY_I(x0,x1,x2,x3,W1,W2,W3,y0,y1,y2,y3) do { \
  f32x2 u1 = pk_cmulj(x1,W1), u2 = pk_cmulj(x2,W2), u3 = pk_cmulj(x3,W3); \
  f32x2 t0 = pk_add(x0,u2), t1 = pk_add(u1,u3), t2 = pk_sub(x0,u2), d_ = pk_sub(u1,u3); \
  y0 = pk_add(t0,t1); y1 = pk_addrot_p(t2,d_); \
  y2 = pk_sub(t0,t1); y3 = pk_addrot_m(t2,d_); } while(0)

#define BFLY_I1(x0,x1,x2,x3,y0,y1,y2,y3) do { \
  f32x2 t0 = pk_add(x0,x2), t1 = pk_add(x1,x3), t2 = pk_sub(x0,x2), d_ = pk_sub(x1,x3); \
  y0 = pk_add(t0,t1); y1 = pk_addrot_p(t2,d_); \
  y2 = pk_sub(t0,t1); y3 = pk_addrot_m(t2,d_); } while(0)

__global__ void k_twiddle(f32x2* __restrict__ tw) {
  int m = blockIdx.x * 256 + threadIdx.x;
  float th = (float)(2.0 * M_PI / 1024.0) * (float)m;
  tw[m] = mk2(cosf(th), -sinf(th));
}

// Forward FFT-1024 (radix-4 DIF). One wave per row, 4 rows/block. Real input.
// dst values are multiplied by `scale`.
__global__ __launch_bounds__(256, 3) void k_fft_fwd(
    const float* __restrict__ src, int estride, int rstride,
    const f32x2* __restrict__ tw, f32x2* __restrict__ dst, float scale,
    const float* __restrict__ vbias, float* __restrict__ out, int dorow) {
  __shared__ __align__(16) f32x2 fft[4][1024];
  int tid = threadIdx.x, wv = tid >> 6, u = tid & 63;
  int row = blockIdx.x * 4 + wv;
  const float* xr = src + (size_t)row * rstride;
  f32x2* L = fft[wv];
  f32x2 twu = tw[u];
  f32x2 tw4u = tw[4 * u];
  int tp = u & 3;
  f32x2 tw16t = tw[16 * tp], tw64t = tw[64 * tp];

  float vr[4][4]; float rs = 0.f;
  #pragma unroll
  for (int a = 0; a < 4; ++a)
    #pragma unroll
    for (int k = 0; k < 4; ++k) {
      float s = xr[(u + 64 * a + 256 * k) * estride];
      vr[a][k] = s; rs += s;
    }
  f32x2 v[4][4];
  #pragma unroll
  for (int a = 0; a < 4; ++a) {
    float x0 = vr[a][0], x1 = vr[a][1], x2 = vr[a][2], x3 = vr[a][3];
    float t0 = x0 + x2, t1 = x1 + x3, t2 = x0 - x2, dm = x1 - x3;
    f32x2 W1 = cmul(twu, Ctw(64 * a));
    f32x2 W2 = cmul(W1, W1), W3 = cmul(W1, W2);
    v[a][0] = mk2(t0 + t1, 0.f);
    v[a][1] = cmul(mk2(t2, -dm), W1);
    v[a][2] = cmul(mk2(t0 - t1, 0.f), W2);
    v[a][3] = cmul(mk2(t2, dm), W3);
  }
  {
    f32x2 W1 = tw4u, W2 = cmul(W1, W1), W3 = cmul(W1, W2);
    #pragma unroll
    for (int k = 0; k < 4; ++k) {
      f32x2 y0,y1,y2,y3;
      BFLY_F(v[0][k], v[1][k], v[2][k], v[3][k], W1, W2, W3, y0,y1,y2,y3);
      v[0][k]=y0; v[1][k]=y1; v[2][k]=y2; v[3][k]=y3;
    }
  }
  #pragma unroll
  for (int a = 0; a < 4; ++a)
    #pragma unroll
    for (int k = 0; k < 4; ++k)
      L[LSW(u + 64 * a + 256 * k)] = v[a][k];

  int D = u >> 2;
  f32x2 w[4][4];
  #pragma unroll
  for (int c = 0; c < 4; ++c)
    #pragma unroll
    for (int ap = 0; ap < 4; ++ap)
      w[c][ap] = L[LSW(64 * D + 16 * c + 4 * ap + tp)];
  #pragma unroll
  for (int ap = 0; ap < 4; ++ap) {
    f32x2 W1 = cmul(Ctw(64 * ap), tw16t);
    f32x2 W2 = cmul(W1, W1), W3 = cmul(W1, W2);
    f32x2 y0,y1,y2,y3;
    BFLY_F(w[0][ap], w[1][ap], w[2][ap], w[3][ap], W1, W2, W3, y0,y1,y2,y3);
    w[0][ap]=y0; w[1][ap]=y1; w[2][ap]=y2; w[3][ap]=y3;
  }
  {
    f32x2 W1 = tw64t, W2 = cmul(W1, W1), W3 = cmul(W1, W2);
    #pragma unroll
    for (int c = 0; c < 4; ++c) {
      f32x2 y0,y1,y2,y3;
      BFLY_F(w[c][0], w[c][1], w[c][2], w[c][3], W1, W2, W3, y0,y1,y2,y3);
      w[c][0]=y0; w[c][1]=y1; w[c][2]=y2; w[c][3]=y3;
    }
  }
  #pragma unroll
  for (int c = 0; c < 4; ++c)
    #pragma unroll
    for (int ap = 0; ap < 4; ++ap)
      L[LSW(64 * D + 16 * c + 4 * ap + tp)] = w[c][ap];

  f32x2* drow = dst + (size_t)row * 1024;
  #pragma unroll
  for (int j = 0; j < 4; ++j) {
    f32x2 z0 = L[LSW(16 * u + 4 * j)];
    f32x2 z1 = L[LSW(16 * u + 4 * j + 1)];
    f32x2 z2 = L[LSW(16 * u + 4 * j + 2)];
    f32x2 z3 = L[LSW(16 * u + 4 * j + 3)];
    f32x2 t0 = z0+z2, t1 = z1+z3, t2 = z0-z2, d = z1-z3;
    f32x2 t3 = mk2(d.y, -d.x);
    f32x2 y0 = (t0+t1)*scale, y1 = (t2+t3)*scale, y2 = (t0-t1)*scale, y3 = (t2-t3)*scale;
    float4* dp = (float4*)(drow + 16 * u + 4 * j);
    dp[0] = make_float4(y0.x, y0.y, y1.x, y1.y);
    dp[1] = make_float4(y2.x, y2.y, y3.x, y3.y);
  }
  if (dorow) {
    #pragma unroll
    for (int m = 32; m; m >>= 1) rs += __shfl_down(rs, m);
    if (u == 0) out[row] = vbias[0] * rs;
  }
}

// ---- k_corr phase macros: padded LDS (phys = s + s>>4), packed-asm math ----

#define PW(M, XA, XB, ZA, ZB) do { \
  float4 qa = W0p[M], qb = W1p[M]; \
  f32x2 g1 = pk_cmulj(mk2(qa.x,qa.y), XA); \
  f32x2 g2 = pk_cmulj(mk2(qb.x,qb.y), XA); \
  ZA = pk_addrot_p(g1, g2); \
  g1 = pk_cmulj(mk2(qa.z,qa.w), XB); \
  g2 = pk_cmulj(mk2(qb.z,qb.w), XB); \
  ZB = pk_addrot_p(g1, g2); } while(0)

// phase A: pointwise + s0 + s1; store logical 16u+i at phys 17u+i (LPA = L+17u)
#define QP_A(P, LPA) do { \
  const float4* W0p = (const float4*)(Wfs + (size_t)(2*(P)) * 1024 + s16); \
  const float4* W1p = (const float4*)(Wfs + (size_t)(2*(P) + 1) * 1024 + s16); \
  f32x2 z0,z1,z2,z3,z4,z5,z6,z7,z8,z9,z10,z11,z12,z13,z14,z15; \
  PW(0, xr0, xr1, z0, z1);   PW(1, xr2, xr3, z2, z3); \
  PW(2, xr4, xr5, z4, z5);   PW(3, xr6, xr7, z6, z7); \
  PW(4, xr8, xr9, z8, z9);   PW(5, xr10, xr11, z10, z11); \
  PW(6, xr12, xr13, z12, z13); PW(7, xr14, xr15, z14, z15); \
  BFLY_I1(z0,z1,z2,z3, z0,z1,z2,z3); \
  BFLY_I1(z4,z5,z6,z7, z4,z5,z6,z7); \
  BFLY_I1(z8,z9,z10,z11, z8,z9,z10,z11); \
  BFLY_I1(z12,z13,z14,z15, z12,z13,z14,z15); \
  BFLY_I1(z0,z4,z8,z12, z0,z4,z8,z12); \
  BFLY_I(z1,z5,z9,z13, Ctw(64),Ctw(128),Ctw(192), z1,z5,z9,z13); \
  BFLY_I(z2,z6,z10,z14, Ctw(128),Ctw(256),Ctw(384), z2,z6,z10,z14); \
  BFLY_I(z3,z7,z11,z15, Ctw(192),Ctw(384),Ctw(576), z3,z7,z11,z15); \
  (LPA)[0]=z0;   (LPA)[1]=z1;   (LPA)[2]=z2;   (LPA)[3]=z3; \
  (LPA)[4]=z4;   (LPA)[5]=z5;   (LPA)[6]=z6;   (LPA)[7]=z7; \
  (LPA)[8]=z8;   (LPA)[9]=z9;   (LPA)[10]=z10; (LPA)[11]=z11; \
  (LPA)[12]=z12; (LPA)[13]=z13; (LPA)[14]=z14; (LPA)[15]=z15; \
} while(0)

// phase B: logical 256B'+64c+16a+t -> phys (272B'+t) + (68c+17a)
#define QP_B(LPB) do { \
  f32x2 w00,w01,w02,w03,w10,w11,w12,w13,w20,w21,w22,w23,w30,w31,w32,w33; \
  w00 = (LPB)[0];   w01 = (LPB)[68];  w02 = (LPB)[136]; w03 = (LPB)[204]; \
  w10 = (LPB)[17];  w11 = (LPB)[85];  w12 = (LPB)[153]; w13 = (LPB)[221]; \
  w20 = (LPB)[34];  w21 = (LPB)[102]; w22 = (LPB)[170]; w23 = (LPB)[238]; \
  w30 = (LPB)[51];  w31 = (LPB)[119]; w32 = (LPB)[187]; w33 = (LPB)[255]; \
  BFLY_I(w00,w10,w20,w30, TB1,TB2,TB3, w00,w10,w20,w30); \
  BFLY_I(w01,w11,w21,w31, TB1,TB2,TB3, w01,w11,w21,w31); \
  BFLY_I(w02,w12,w22,w32, TB1,TB2,TB3, w02,w12,w22,w32); \
  BFLY_I(w03,w13,w23,w33, TB1,TB2,TB3, w03,w13,w23,w33); \
  BFLY_I(w00,w01,w02,w03, TC10,TC20,TC30, w00,w01,w02,w03); \
  BFLY_I(w10,w11,w12,w13, TC11,TC21,TC31, w10,w11,w12,w13); \
  BFLY_I(w20,w21,w22,w23, TC12,TC22,TC32, w20,w21,w22,w23); \
  BFLY_I(w30,w31,w32,w33, TC13,TC23,TC33, w30,w31,w32,w33); \
  (LPB)[0]=w00;   (LPB)[68]=w01;  (LPB)[136]=w02; (LPB)[204]=w03; \
  (LPB)[17]=w10;  (LPB)[85]=w11;  (LPB)[153]=w12; (LPB)[221]=w13; \
  (LPB)[34]=w20;  (LPB)[102]=w21; (LPB)[170]=w22; (LPB)[238]=w23; \
  (LPB)[51]=w30;  (LPB)[119]=w31; (LPB)[187]=w32; (LPB)[255]=w33; \
} while(0)

// log2-domain logcosh: u already = |v+b|*2/ln2 (scale folded); one log2 per pair
#define LCACC(C, B2, ACC) do { \
  f32x2 t2_ = pk_add((C), (B2)); \
  f32x2 u2_ = pk_nabs(t2_); \
  float p_ = (1.f + fast_exp2(-u2_.x)) * (1.f + fast_exp2(-u2_.y)); \
  ACC += fast_log2(p_); \
  accU = pk_add(accU, u2_); } while(0)

// phase C: logical 4u+I+256k -> phys (4u+(u>>2)) + (I+272k)
#define QPC_PH(LPC, I, T1, T2, T3, B2) do { \
  f32x2 c0 = (LPC)[(I)],     c1 = (LPC)[(I)+272]; \
  f32x2 c2 = (LPC)[(I)+544], c3 = (LPC)[(I)+816]; \
  BFLY_I(c0,c1,c2,c3,T1,T2,T3,c0,c1,c2,c3); \
  LCACC(c0, B2, accL0); LCACC(c1, B2, accL1); \
  LCACC(c2, B2, accL0); LCACC(c3, B2, accL1); } while(0)

#define QP_C(LPC, B2) do { \
  QPC_PH(LPC, 0, TD10, TD20, TD30, B2); \
  QPC_PH(LPC, 1, TD11, TD21, TD31, B2); \
  QPC_PH(LPC, 2, TD12, TD22, TD32, B2); \
  QPC_PH(LPC, 3, TD13, TD23, TD33, B2); } while(0)

// 256 thr = 4 waves; wave wv owns TWO passes (j-pairs (4wv,4wv+1),(4wv+2,4wv+3)),
// pipelined A0 A1 | B0 B1 | C0 C1 on disjoint LDS buffers (cross-pass ILP).
__global__ __launch_bounds__(256, 2) void k_corr(
    const f32x2* __restrict__ X, const f32x2* __restrict__ Wfs,
    const float* __restrict__ bs, const f32x2* __restrict__ tw,
    float* __restrict__ out) {
  __shared__ __align__(16) f32x2 LBW[4][2][1088];   // [wave][pass][slot]
  __shared__ float red[4];
  int tid = threadIdx.x, wv = tid >> 6, u = tid & 63;
  int b = blockIdx.x;
  f32x2* L0 = LBW[wv][0];
  f32x2* L1 = LBW[wv][1];
  f32x2* LPA0 = L0 + 17 * u;
  f32x2* LPA1 = L1 + 17 * u;
  f32x2* LPB0 = L0 + 272 * (u >> 4) + (u & 15);
  f32x2* LPB1 = L1 + 272 * (u >> 4) + (u & 15);
  f32x2* LPC0 = L0 + 4 * u + (u >> 2);
  f32x2* LPC1 = L1 + 4 * u + (u >> 2);
  f32x2 tw4u = tw[4 * u];
  int t = u & 15;
  f32x2 tw16t = tw[16 * t], tw4t = tw[4 * t];
  int s16 = 16 * u;

  f32x2 xr0,xr1,xr2,xr3,xr4,xr5,xr6,xr7,xr8,xr9,xr10,xr11,xr12,xr13,xr14,xr15;
  {
    const float4* Xp = (const float4*)(X + (size_t)b * 1024 + s16);
    float4 q;
    q = Xp[0]; xr0  = mk2(q.x,q.y); xr1  = mk2(q.z,q.w);
    q = Xp[1]; xr2  = mk2(q.x,q.y); xr3  = mk2(q.z,q.w);
    q = Xp[2]; xr4  = mk2(q.x,q.y); xr5  = mk2(q.z,q.w);
    q = Xp[3]; xr6  = mk2(q.x,q.y); xr7  = mk2(q.z,q.w);
    q = Xp[4]; xr8  = mk2(q.x,q.y); xr9  = mk2(q.z,q.w);
    q = Xp[5]; xr10 = mk2(q.x,q.y); xr11 = mk2(q.z,q.w);
    q = Xp[6]; xr12 = mk2(q.x,q.y); xr13 = mk2(q.z,q.w);
    q = Xp[7]; xr14 = mk2(q.x,q.y); xr15 = mk2(q.z,q.w);
  }
  f32x2 bias20 = mk2(bs[4*wv]   * TWO_OVER_LN2, bs[4*wv+1] * TWO_OVER_LN2);
  f32x2 bias21 = mk2(bs[4*wv+2] * TWO_OVER_LN2, bs[4*wv+3] * TWO_OVER_LN2);

  // phase A of both passes
  QP_A(2*wv,     LPA0);
  QP_A(2*wv + 1, LPA1);

  // s2/s3 twiddles (shared by both passes)
  f32x2 TB1 = tw16t, TB2 = pk_cmul(TB1,TB1), TB3 = pk_cmul(TB1,TB2);
  f32x2 TC10 = tw4t,                  TC20 = pk_cmul(TC10,TC10), TC30 = pk_cmul(TC10,TC20);
  f32x2 TC11 = pk_cmul(tw4t,Ctw(64)),  TC21 = pk_cmul(TC11,TC11), TC31 = pk_cmul(TC11,TC21);
  f32x2 TC12 = pk_cmul(tw4t,Ctw(128)), TC22 = pk_cmul(TC12,TC12), TC32 = pk_cmul(TC12,TC22);
  f32x2 TC13 = pk_cmul(tw4t,Ctw(192)), TC23 = pk_cmul(TC13,TC13), TC33 = pk_cmul(TC13,TC23);

  // phase B of both passes
  QP_B(LPB0);
  QP_B(LPB1);

  // s4 twiddles (shared)
  f32x2 TD10 = tw4u,                 TD20 = pk_cmul(TD10,TD10), TD30 = pk_cmul(TD10,TD20);
  f32x2 TD11 = pk_cmul(tw4u,Ctw(1)), TD21 = pk_cmul(TD11,TD11), TD31 = pk_cmul(TD11,TD21);
  f32x2 TD12 = pk_cmul(tw4u,Ctw(2)), TD22 = pk_cmul(TD12,TD12), TD32 = pk_cmul(TD12,TD22);
  f32x2 TD13 = pk_cmul(tw4u,Ctw(3)), TD23 = pk_cmul(TD13,TD13), TD33 = pk_cmul(TD13,TD23);

  // phase C of both passes (log2-domain logcosh)
  float accL0 = 0.f, accL1 = 0.f;
  f32x2 accU = mk2(0.f, 0.f);
  QP_C(LPC0, bias20);
  QP_C(LPC1, bias21);

  float acc = (accL0 + accL1) + 0.5f * (accU.x + accU.y);
  #pragma unroll
  for (int m = 32; m; m >>= 1) acc += __shfl_down(acc, m);
  if (u == 0) red[wv] = acc;
  __syncthreads();
  if (tid == 0) {
    float s = (red[0] + red[1]) + (red[2] + red[3]);
    out[b] += LN2F * (s - 16384.f);
  }
}

// fallback if workspace is too small: correct but slow
__global__ void k_naive(const float* __restrict__ x, const float* __restrict__ W,
                        const float* __restrict__ bs, const float* __restrict__ vb,
                        float* __restrict__ out) {
  int b = blockIdx.x;
  __shared__ float xs[1024];
  __shared__ float red[256];
  int t = threadIdx.x;
  float xsum = 0.f;
  for (int i = t; i < 1024; i += 256) { float v = x[(size_t)b * 1024 + i]; xs[i] = v; xsum += v; }
  __syncthreads();
  float tot = vb[0] * xsum;
  for (int h = t; h < 16384; h += 256) {
    int j = h >> 10, kh = h & 1023;
    float a = bs[j];
    for (int i = 0; i < 1024; ++i) a += xs[i] * W[((i + kh) & 1023) * 16 + j];
    float ax = fabsf(a);
    tot += ax + __logf(1.f + __expf(-2.f * ax)) - LN2F;
  }
  red[t] = tot;
  __syncthreads();
  for (int s2 = 128; s2; s2 >>= 1) { if (t < s2) red[t] += red[t + s2]; __syncthreads(); }
  if (t == 0) out[b] = red[0];
}

extern "C" void kernel_launch(void* const* d_in, const int* in_sizes, int n_in,
                              void* d_out, int out_size, void* d_ws, size_t ws_size,
                              hipStream_t stream) {
  const float* x  = (const float*)d_in[0];   // [4096,1024]
  const float* W  = (const float*)d_in[1];   // [1024,16]
  const float* bs = (const float*)d_in[2];   // [16]
  const float* vb = (const float*)d_in[3];   // [1]
  float* out = (float*)d_out;                // [4096]

  size_t need = 8192 + 131072 + (size_t)4096 * 1024 * 8;  // tw + Wfs + X
  if (ws_size < need) {
    k_naive<<<4096, 256, 0, stream>>>(x, W, bs, vb, out);
    return;
  }
  f32x2* tw  = (f32x2*)d_ws;
  f32x2* Wfs = (f32x2*)((char*)d_ws + 8192);
  f32x2* X   = (f32x2*)((char*)d_ws + 8192 + 131072);

  k_twiddle<<<4, 256, 0, stream>>>(tw);
  // 16 W-column spectra scaled by (1/1024)*(2/ln2) -- folds IFFT norm + logcosh scale
  k_fft_fwd<<<4, 256, 0, stream>>>(W, 16, 1, tw, Wfs, SCL * TWO_OVER_LN2, vb, out, 0);
  // 4096 x-row spectra; also out[row] = vb * rowsum(x[row])
  k_fft_fwd<<<1024, 256, 0, stream>>>(x, 1, 1024, tw, X, 1.0f, vb, out, 1);
  k_corr<<<4096, 256, 0, stream>>>(X, Wfs, bs, tw, out);
}

// Round 18
// 122.830 us; speedup vs baseline: 1.4806x; 1.0527x over previous
//
#include <hip/hip_runtime.h>
#include <hip/hip_bf16.h>
#include <math.h>

#define LN2F 0.6931471805599453f
#define SCL 9.765625e-4f       // 1/1024
#define TWO_OVER_LN2 2.885390081777927f

typedef __attribute__((ext_vector_type(2))) float f32x2;

// ---------------------------------------------------------------------------
// Circulant trick: y[b, j*1024+i] = sum_k x[b,k] W[(i+k)%1024, j] is circular
// cross-correlation -> y_row = IDFT( Wf_j * conj(X_b) ), length-1024.
// Order irrelevant under sum(logcosh): radix-4 DIF forward + adjoint radix-4
// DIT inverse, no bit reversal. 2 real outputs per complex IFFT.
// k_corr (r15 structure, best measured ~105us): 256 thr / 4 waves, wave owns
// TWO packed IFFT passes phase-pipelined A0 A1 | B0 B1 | C0 C1 on disjoint
// padded LDS buffers (phys = s + s>>4, base+imm, conflict-free).
// r18: forward FFT butterflies ported to the same validated VOP3P asm
// (halves fwd instr count) and the W-FFT + x-FFT merged into one dispatch.
// Complex math = v_pk_mul/fma/add with op_sel/neg (no v_pk_max_f32 on
// gfx950). logcosh in log2 domain, one log2 per pair. 2/ln2 folded into Wfs.
// Zero per-thread arrays (r7 spill lesson).
// ---------------------------------------------------------------------------

#define LSW(s) ((s) ^ (((s) >> 4) & 15))   // (fwd kernel LDS swizzle)

__device__ __forceinline__ f32x2 mk2(float x, float y) { f32x2 r; r.x = x; r.y = y; return r; }

// ---- VOP3P packed helpers (validated bit-exact through r14-r17) ----
__device__ __forceinline__ f32x2 pk_cmul(f32x2 a, f32x2 b) {   // a*b
  f32x2 d, t;
  asm("v_pk_mul_f32 %1, %2, %3 op_sel:[0,0] op_sel_hi:[0,1]\n\t"
      "v_pk_fma_f32 %0, %2, %3, %1 op_sel:[1,1,0] op_sel_hi:[1,0,1] neg_lo:[1,0,0]"
      : "=v"(d), "=&v"(t) : "v"(a), "v"(b));
  return d;
}
__device__ __forceinline__ f32x2 pk_cmulj(f32x2 a, f32x2 b) {  // a*conj(b)
  f32x2 d, t;
  asm("v_pk_mul_f32 %1, %2, %3 op_sel:[0,0] op_sel_hi:[0,1] neg_hi:[0,1]\n\t"
      "v_pk_fma_f32 %0, %2, %3, %1 op_sel:[1,1,0] op_sel_hi:[1,0,1]"
      : "=v"(d), "=&v"(t) : "v"(a), "v"(b));
  return d;
}
__device__ __forceinline__ f32x2 pk_add(f32x2 a, f32x2 b) {
  f32x2 o;
  asm("v_pk_add_f32 %0, %1, %2" : "=v"(o) : "v"(a), "v"(b));
  return o;
}
__device__ __forceinline__ f32x2 pk_sub(f32x2 a, f32x2 b) {
  f32x2 o;
  asm("v_pk_add_f32 %0, %1, %2 neg_lo:[0,1] neg_hi:[0,1]" : "=v"(o) : "v"(a), "v"(b));
  return o;
}
__device__ __forceinline__ f32x2 pk_addrot_p(f32x2 a, f32x2 d) {  // a + i*d
  f32x2 o;
  asm("v_pk_add_f32 %0, %1, %2 op_sel:[0,1] op_sel_hi:[1,0] neg_lo:[0,1]"
      : "=v"(o) : "v"(a), "v"(d));
  return o;
}
__device__ __forceinline__ f32x2 pk_addrot_m(f32x2 a, f32x2 d) {  // a - i*d
  f32x2 o;
  asm("v_pk_add_f32 %0, %1, %2 op_sel:[0,1] op_sel_hi:[1,0] neg_hi:[0,1]"
      : "=v"(o) : "v"(a), "v"(d));
  return o;
}
__device__ __forceinline__ f32x2 pk_nabs(f32x2 a) {  // |a| elementwise
  return mk2(fabsf(a.x), fabsf(a.y));
}

__device__ __forceinline__ float fast_exp2(float x) {
#if __has_builtin(__builtin_amdgcn_exp2f)
  return __builtin_amdgcn_exp2f(x);
#else
  return exp2f(x);
#endif
}
__device__ __forceinline__ float fast_log2(float x) {
#if __has_builtin(__builtin_amdgcn_logf)
  return __builtin_amdgcn_logf(x);
#else
  return __log2f(x);
#endif
}

// TWF[m] = e^{-2*pi*i*m/1024} for the compile-time m we need
__device__ __forceinline__ f32x2 Ctw(int m) {
  switch (m) {
    case 0:   return mk2(1.f, 0.f);
    case 1:   return mk2(0.999981175f, -0.006135885f);
    case 2:   return mk2(0.999924702f, -0.012271538f);
    case 3:   return mk2(0.999830582f, -0.018406730f);
    case 64:  return mk2(0.923879533f, -0.382683432f);
    case 128: return mk2(0.707106781f, -0.707106781f);
    case 192: return mk2(0.382683432f, -0.923879533f);
    case 256: return mk2(0.f, -1.f);
    case 384: return mk2(-0.707106781f, -0.707106781f);
    case 576: return mk2(-0.923879533f, 0.382683432f);
  }
  return mk2(1.f, 0.f);
}

// forward DIF butterfly (output twiddles, e^{-}) -- packed asm
// t3 = -i*d, so t2+t3 = t2 - i*d (addrot_m), t2-t3 = t2 + i*d (addrot_p)
#define BFLY_F(x0,x1,x2,x3,W1,W2,W3,y0,y1,y2,y3) do { \
  f32x2 t0 = pk_add(x0,x2), t1 = pk_add(x1,x3), t2 = pk_sub(x0,x2), d_ = pk_sub(x1,x3); \
  y0 = pk_add(t0,t1); y1 = pk_cmul(pk_addrot_m(t2,d_), W1); \
  y2 = pk_cmul(pk_sub(t0,t1), W2); y3 = pk_cmul(pk_addrot_p(t2,d_), W3); } while(0)

// inverse DIT butterfly (input conj-twiddles, e^{+}) -- packed asm
#define BFLY_I(x0,x1,x2,x3,W1,W2,W3,y0,y1,y2,y3) do { \
  f32x2 u1 = pk_cmulj(x1,W1), u2 = pk_cmulj(x2,W2), u3 = pk_cmulj(x3,W3); \
  f32x2 t0 = pk_add(x0,u2), t1 = pk_add(u1,u3), t2 = pk_sub(x0,u2), d_ = pk_sub(u1,u3); \
  y0 = pk_add(t0,t1); y1 = pk_addrot_p(t2,d_); \
  y2 = pk_sub(t0,t1); y3 = pk_addrot_m(t2,d_); } while(0)

#define BFLY_I1(x0,x1,x2,x3,y0,y1,y2,y3) do { \
  f32x2 t0 = pk_add(x0,x2), t1 = pk_add(x1,x3), t2 = pk_sub(x0,x2), d_ = pk_sub(x1,x3); \
  y0 = pk_add(t0,t1); y1 = pk_addrot_p(t2,d_); \
  y2 = pk_sub(t0,t1); y3 = pk_addrot_m(t2,d_); } while(0)

__global__ void k_twiddle(f32x2* __restrict__ tw) {
  int m = blockIdx.x * 256 + threadIdx.x;
  float th = (float)(2.0 * M_PI / 1024.0) * (float)m;
  tw[m] = mk2(cosf(th), -sinf(th));
}

// Merged forward FFT-1024 (radix-4 DIF, packed asm). One wave per row,
// 4 rows/block. Blocks 0..3: W columns -> Wfs (scaled); blocks 4..1027:
// x rows -> X (+ vb*rowsum into out).
__global__ __launch_bounds__(256, 3) void k_fft_fwd(
    const float* __restrict__ W, const float* __restrict__ x,
    const f32x2* __restrict__ tw, f32x2* __restrict__ Wfs, f32x2* __restrict__ X,
    const float* __restrict__ vbias, float* __restrict__ out) {
  __shared__ __align__(16) f32x2 fft[4][1024];
  int tid = threadIdx.x, wv = tid >> 6, u = tid & 63;
  int bb = blockIdx.x;
  int isw = (bb < 4);
  int row = (isw ? bb : bb - 4) * 4 + wv;
  const float* xr = isw ? (W + row) : (x + (size_t)row * 1024);
  int estride = isw ? 16 : 1;
  float scale = isw ? (SCL * TWO_OVER_LN2) : 1.0f;
  f32x2* drow = (isw ? Wfs : X) + (size_t)row * 1024;

  f32x2* L = fft[wv];
  f32x2 twu = tw[u];
  f32x2 tw4u = tw[4 * u];
  int tp = u & 3;
  f32x2 tw16t = tw[16 * tp], tw64t = tw[64 * tp];

  float vr[4][4]; float rs = 0.f;
  #pragma unroll
  for (int a = 0; a < 4; ++a)
    #pragma unroll
    for (int k = 0; k < 4; ++k) {
      float s = xr[(u + 64 * a + 256 * k) * estride];
      vr[a][k] = s; rs += s;
    }
  f32x2 v[4][4];
  #pragma unroll
  for (int a = 0; a < 4; ++a) {
    float x0 = vr[a][0], x1 = vr[a][1], x2 = vr[a][2], x3 = vr[a][3];
    float t0 = x0 + x2, t1 = x1 + x3, t2 = x0 - x2, dm = x1 - x3;
    f32x2 W1 = pk_cmul(twu, Ctw(64 * a));
    f32x2 W2 = pk_cmul(W1, W1), W3 = pk_cmul(W1, W2);
    v[a][0] = mk2(t0 + t1, 0.f);
    v[a][1] = pk_cmul(mk2(t2, -dm), W1);
    v[a][2] = pk_cmul(mk2(t0 - t1, 0.f), W2);
    v[a][3] = pk_cmul(mk2(t2, dm), W3);
  }
  {
    f32x2 W1 = tw4u, W2 = pk_cmul(W1, W1), W3 = pk_cmul(W1, W2);
    #pragma unroll
    for (int k = 0; k < 4; ++k) {
      f32x2 y0,y1,y2,y3;
      BFLY_F(v[0][k], v[1][k], v[2][k], v[3][k], W1, W2, W3, y0,y1,y2,y3);
      v[0][k]=y0; v[1][k]=y1; v[2][k]=y2; v[3][k]=y3;
    }
  }
  #pragma unroll
  for (int a = 0; a < 4; ++a)
    #pragma unroll
    for (int k = 0; k < 4; ++k)
      L[LSW(u + 64 * a + 256 * k)] = v[a][k];

  int D = u >> 2;
  f32x2 w[4][4];
  #pragma unroll
  for (int c = 0; c < 4; ++c)
    #pragma unroll
    for (int ap = 0; ap < 4; ++ap)
      w[c][ap] = L[LSW(64 * D + 16 * c + 4 * ap + tp)];
  #pragma unroll
  for (int ap = 0; ap < 4; ++ap) {
    f32x2 W1 = pk_cmul(Ctw(64 * ap), tw16t);
    f32x2 W2 = pk_cmul(W1, W1), W3 = pk_cmul(W1, W2);
    f32x2 y0,y1,y2,y3;
    BFLY_F(w[0][ap], w[1][ap], w[2][ap], w[3][ap], W1, W2, W3, y0,y1,y2,y3);
    w[0][ap]=y0; w[1][ap]=y1; w[2][ap]=y2; w[3][ap]=y3;
  }
  {
    f32x2 W1 = tw64t, W2 = pk_cmul(W1, W1), W3 = pk_cmul(W1, W2);
    #pragma unroll
    for (int c = 0; c < 4; ++c) {
      f32x2 y0,y1,y2,y3;
      BFLY_F(w[c][0], w[c][1], w[c][2], w[c][3], W1, W2, W3, y0,y1,y2,y3);
      w[c][0]=y0; w[c][1]=y1; w[c][2]=y2; w[c][3]=y3;
    }
  }
  #pragma unroll
  for (int c = 0; c < 4; ++c)
    #pragma unroll
    for (int ap = 0; ap < 4; ++ap)
      L[LSW(64 * D + 16 * c + 4 * ap + tp)] = w[c][ap];

  #pragma unroll
  for (int j = 0; j < 4; ++j) {
    f32x2 z0 = L[LSW(16 * u + 4 * j)];
    f32x2 z1 = L[LSW(16 * u + 4 * j + 1)];
    f32x2 z2 = L[LSW(16 * u + 4 * j + 2)];
    f32x2 z3 = L[LSW(16 * u + 4 * j + 3)];
    f32x2 t0 = pk_add(z0,z2), t1 = pk_add(z1,z3), t2 = pk_sub(z0,z2), d = pk_sub(z1,z3);
    f32x2 y0 = pk_add(t0,t1) * scale, y1 = pk_addrot_m(t2,d) * scale;
    f32x2 y2 = pk_sub(t0,t1) * scale, y3 = pk_addrot_p(t2,d) * scale;
    float4* dp = (float4*)(drow + 16 * u + 4 * j);
    dp[0] = make_float4(y0.x, y0.y, y1.x, y1.y);
    dp[1] = make_float4(y2.x, y2.y, y3.x, y3.y);
  }
  if (!isw) {
    #pragma unroll
    for (int m = 32; m; m >>= 1) rs += __shfl_down(rs, m);
    if (u == 0) out[row] = vbias[0] * rs;
  }
}

// ---- k_corr phase macros: padded LDS (phys = s + s>>4), packed-asm math ----

#define PW(M, XA, XB, ZA, ZB) do { \
  float4 qa = W0p[M], qb = W1p[M]; \
  f32x2 g1 = pk_cmulj(mk2(qa.x,qa.y), XA); \
  f32x2 g2 = pk_cmulj(mk2(qb.x,qb.y), XA); \
  ZA = pk_addrot_p(g1, g2); \
  g1 = pk_cmulj(mk2(qa.z,qa.w), XB); \
  g2 = pk_cmulj(mk2(qb.z,qb.w), XB); \
  ZB = pk_addrot_p(g1, g2); } while(0)

// phase A: pointwise + s0 + s1; store logical 16u+i at phys 17u+i (LPA = L+17u)
#define QP_A(P, LPA) do { \
  const float4* W0p = (const float4*)(Wfs + (size_t)(2*(P)) * 1024 + s16); \
  const float4* W1p = (const float4*)(Wfs + (size_t)(2*(P) + 1) * 1024 + s16); \
  f32x2 z0,z1,z2,z3,z4,z5,z6,z7,z8,z9,z10,z11,z12,z13,z14,z15; \
  PW(0, xr0, xr1, z0, z1);   PW(1, xr2, xr3, z2, z3); \
  PW(2, xr4, xr5, z4, z5);   PW(3, xr6, xr7, z6, z7); \
  PW(4, xr8, xr9, z8, z9);   PW(5, xr10, xr11, z10, z11); \
  PW(6, xr12, xr13, z12, z13); PW(7, xr14, xr15, z14, z15); \
  BFLY_I1(z0,z1,z2,z3, z0,z1,z2,z3); \
  BFLY_I1(z4,z5,z6,z7, z4,z5,z6,z7); \
  BFLY_I1(z8,z9,z10,z11, z8,z9,z10,z11); \
  BFLY_I1(z12,z13,z14,z15, z12,z13,z14,z15); \
  BFLY_I1(z0,z4,z8,z12, z0,z4,z8,z12); \
  BFLY_I(z1,z5,z9,z13, Ctw(64),Ctw(128),Ctw(192), z1,z5,z9,z13); \
  BFLY_I(z2,z6,z10,z14, Ctw(128),Ctw(256),Ctw(384), z2,z6,z10,z14); \
  BFLY_I(z3,z7,z11,z15, Ctw(192),Ctw(384),Ctw(576), z3,z7,z11,z15); \
  (LPA)[0]=z0;   (LPA)[1]=z1;   (LPA)[2]=z2;   (LPA)[3]=z3; \
  (LPA)[4]=z4;   (LPA)[5]=z5;   (LPA)[6]=z6;   (LPA)[7]=z7; \
  (LPA)[8]=z8;   (LPA)[9]=z9;   (LPA)[10]=z10; (LPA)[11]=z11; \
  (LPA)[12]=z12; (LPA)[13]=z13; (LPA)[14]=z14; (LPA)[15]=z15; \
} while(0)

// phase B: logical 256B'+64c+16a+t -> phys (272B'+t) + (68c+17a)
#define QP_B(LPB) do { \
  f32x2 w00,w01,w02,w03,w10,w11,w12,w13,w20,w21,w22,w23,w30,w31,w32,w33; \
  w00 = (LPB)[0];   w01 = (LPB)[68];  w02 = (LPB)[136]; w03 = (LPB)[204]; \
  w10 = (LPB)[17];  w11 = (LPB)[85];  w12 = (LPB)[153]; w13 = (LPB)[221]; \
  w20 = (LPB)[34];  w21 = (LPB)[102]; w22 = (LPB)[170]; w23 = (LPB)[238]; \
  w30 = (LPB)[51];  w31 = (LPB)[119]; w32 = (LPB)[187]; w33 = (LPB)[255]; \
  BFLY_I(w00,w10,w20,w30, TB1,TB2,TB3, w00,w10,w20,w30); \
  BFLY_I(w01,w11,w21,w31, TB1,TB2,TB3, w01,w11,w21,w31); \
  BFLY_I(w02,w12,w22,w32, TB1,TB2,TB3, w02,w12,w22,w32); \
  BFLY_I(w03,w13,w23,w33, TB1,TB2,TB3, w03,w13,w23,w33); \
  BFLY_I(w00,w01,w02,w03, TC10,TC20,TC30, w00,w01,w02,w03); \
  BFLY_I(w10,w11,w12,w13, TC11,TC21,TC31, w10,w11,w12,w13); \
  BFLY_I(w20,w21,w22,w23, TC12,TC22,TC32, w20,w21,w22,w23); \
  BFLY_I(w30,w31,w32,w33, TC13,TC23,TC33, w30,w31,w32,w33); \
  (LPB)[0]=w00;   (LPB)[68]=w01;  (LPB)[136]=w02; (LPB)[204]=w03; \
  (LPB)[17]=w10;  (LPB)[85]=w11;  (LPB)[153]=w12; (LPB)[221]=w13; \
  (LPB)[34]=w20;  (LPB)[102]=w21; (LPB)[170]=w22; (LPB)[238]=w23; \
  (LPB)[51]=w30;  (LPB)[119]=w31; (LPB)[187]=w32; (LPB)[255]=w33; \
} while(0)

// log2-domain logcosh: u already = |v+b|*2/ln2 (scale folded); one log2 per pair
#define LCACC(C, B2, ACC) do { \
  f32x2 t2_ = pk_add((C), (B2)); \
  f32x2 u2_ = pk_nabs(t2_); \
  float p_ = (1.f + fast_exp2(-u2_.x)) * (1.f + fast_exp2(-u2_.y)); \
  ACC += fast_log2(p_); \
  accU = pk_add(accU, u2_); } while(0)

// phase C: logical 4u+I+256k -> phys (4u+(u>>2)) + (I+272k)
#define QPC_PH(LPC, I, T1, T2, T3, B2) do { \
  f32x2 c0 = (LPC)[(I)],     c1 = (LPC)[(I)+272]; \
  f32x2 c2 = (LPC)[(I)+544], c3 = (LPC)[(I)+816]; \
  BFLY_I(c0,c1,c2,c3,T1,T2,T3,c0,c1,c2,c3); \
  LCACC(c0, B2, accL0); LCACC(c1, B2, accL1); \
  LCACC(c2, B2, accL0); LCACC(c3, B2, accL1); } while(0)

#define QP_C(LPC, B2) do { \
  QPC_PH(LPC, 0, TD10, TD20, TD30, B2); \
  QPC_PH(LPC, 1, TD11, TD21, TD31, B2); \
  QPC_PH(LPC, 2, TD12, TD22, TD32, B2); \
  QPC_PH(LPC, 3, TD13, TD23, TD33, B2); } while(0)

// 256 thr = 4 waves; wave wv owns TWO passes (j-pairs (4wv,4wv+1),(4wv+2,4wv+3)),
// pipelined A0 A1 | B0 B1 | C0 C1 on disjoint LDS buffers (cross-pass ILP).
__global__ __launch_bounds__(256, 2) void k_corr(
    const f32x2* __restrict__ X, const f32x2* __restrict__ Wfs,
    const float* __restrict__ bs, const f32x2* __restrict__ tw,
    float* __restrict__ out) {
  __shared__ __align__(16) f32x2 LBW[4][2][1088];   // [wave][pass][slot]
  __shared__ float red[4];
  int tid = threadIdx.x, wv = tid >> 6, u = tid & 63;
  int b = blockIdx.x;
  f32x2* L0 = LBW[wv][0];
  f32x2* L1 = LBW[wv][1];
  f32x2* LPA0 = L0 + 17 * u;
  f32x2* LPA1 = L1 + 17 * u;
  f32x2* LPB0 = L0 + 272 * (u >> 4) + (u & 15);
  f32x2* LPB1 = L1 + 272 * (u >> 4) + (u & 15);
  f32x2* LPC0 = L0 + 4 * u + (u >> 2);
  f32x2* LPC1 = L1 + 4 * u + (u >> 2);
  f32x2 tw4u = tw[4 * u];
  int t = u & 15;
  f32x2 tw16t = tw[16 * t], tw4t = tw[4 * t];
  int s16 = 16 * u;

  f32x2 xr0,xr1,xr2,xr3,xr4,xr5,xr6,xr7,xr8,xr9,xr10,xr11,xr12,xr13,xr14,xr15;
  {
    const float4* Xp = (const float4*)(X + (size_t)b * 1024 + s16);
    float4 q;
    q = Xp[0]; xr0  = mk2(q.x,q.y); xr1  = mk2(q.z,q.w);
    q = Xp[1]; xr2  = mk2(q.x,q.y); xr3  = mk2(q.z,q.w);
    q = Xp[2]; xr4  = mk2(q.x,q.y); xr5  = mk2(q.z,q.w);
    q = Xp[3]; xr6  = mk2(q.x,q.y); xr7  = mk2(q.z,q.w);
    q = Xp[4]; xr8  = mk2(q.x,q.y); xr9  = mk2(q.z,q.w);
    q = Xp[5]; xr10 = mk2(q.x,q.y); xr11 = mk2(q.z,q.w);
    q = Xp[6]; xr12 = mk2(q.x,q.y); xr13 = mk2(q.z,q.w);
    q = Xp[7]; xr14 = mk2(q.x,q.y); xr15 = mk2(q.z,q.w);
  }
  f32x2 bias20 = mk2(bs[4*wv]   * TWO_OVER_LN2, bs[4*wv+1] * TWO_OVER_LN2);
  f32x2 bias21 = mk2(bs[4*wv+2] * TWO_OVER_LN2, bs[4*wv+3] * TWO_OVER_LN2);

  // phase A of both passes
  QP_A(2*wv,     LPA0);
  QP_A(2*wv + 1, LPA1);

  // s2/s3 twiddles (shared by both passes)
  f32x2 TB1 = tw16t, TB2 = pk_cmul(TB1,TB1), TB3 = pk_cmul(TB1,TB2);
  f32x2 TC10 = tw4t,                  TC20 = pk_cmul(TC10,TC10), TC30 = pk_cmul(TC10,TC20);
  f32x2 TC11 = pk_cmul(tw4t,Ctw(64)),  TC21 = pk_cmul(TC11,TC11), TC31 = pk_cmul(TC11,TC21);
  f32x2 TC12 = pk_cmul(tw4t,Ctw(128)), TC22 = pk_cmul(TC12,TC12), TC32 = pk_cmul(TC12,TC22);
  f32x2 TC13 = pk_cmul(tw4t,Ctw(192)), TC23 = pk_cmul(TC13,TC13), TC33 = pk_cmul(TC13,TC23);

  // phase B of both passes
  QP_B(LPB0);
  QP_B(LPB1);

  // s4 twiddles (shared)
  f32x2 TD10 = tw4u,                 TD20 = pk_cmul(TD10,TD10), TD30 = pk_cmul(TD10,TD20);
  f32x2 TD11 = pk_cmul(tw4u,Ctw(1)), TD21 = pk_cmul(TD11,TD11), TD31 = pk_cmul(TD11,TD21);
  f32x2 TD12 = pk_cmul(tw4u,Ctw(2)), TD22 = pk_cmul(TD12,TD12), TD32 = pk_cmul(TD12,TD22);
  f32x2 TD13 = pk_cmul(tw4u,Ctw(3)), TD23 = pk_cmul(TD13,TD13), TD33 = pk_cmul(TD13,TD23);

  // phase C of both passes (log2-domain logcosh)
  float accL0 = 0.f, accL1 = 0.f;
  f32x2 accU = mk2(0.f, 0.f);
  QP_C(LPC0, bias20);
  QP_C(LPC1, bias21);

  float acc = (accL0 + accL1) + 0.5f * (accU.x + accU.y);
  #pragma unroll
  for (int m = 32; m; m >>= 1) acc += __shfl_down(acc, m);
  if (u == 0) red[wv] = acc;
  __syncthreads();
  if (tid == 0) {
    float s = (red[0] + red[1]) + (red[2] + red[3]);
    out[b] += LN2F * (s - 16384.f);
  }
}

// fallback if workspace is too small: correct but slow
__global__ void k_naive(const float* __restrict__ x, const float* __restrict__ W,
                        const float* __restrict__ bs, const float* __restrict__ vb,
                        float* __restrict__ out) {
  int b = blockIdx.x;
  __shared__ float xs[1024];
  __shared__ float red[256];
  int t = threadIdx.x;
  float xsum = 0.f;
  for (int i = t; i < 1024; i += 256) { float v = x[(size_t)b * 1024 + i]; xs[i] = v; xsum += v; }
  __syncthreads();
  float tot = vb[0] * xsum;
  for (int h = t; h < 16384; h += 256) {
    int j = h >> 10, kh = h & 1023;
    float a = bs[j];
    for (int i = 0; i < 1024; ++i) a += xs[i] * W[((i + kh) & 1023) * 16 + j];
    float ax = fabsf(a);
    tot += ax + __logf(1.f + __expf(-2.f * ax)) - LN2F;
  }
  red[t] = tot;
  __syncthreads();
  for (int s2 = 128; s2; s2 >>= 1) { if (t < s2) red[t] += red[t + s2]; __syncthreads(); }
  if (t == 0) out[b] = red[0];
}

extern "C" void kernel_launch(void* const* d_in, const int* in_sizes, int n_in,
                              void* d_out, int out_size, void* d_ws, size_t ws_size,
                              hipStream_t stream) {
  const float* x  = (const float*)d_in[0];   // [4096,1024]
  const float* W  = (const float*)d_in[1];   // [1024,16]
  const float* bs = (const float*)d_in[2];   // [16]
  const float* vb = (const float*)d_in[3];   // [1]
  float* out = (float*)d_out;                // [4096]

  size_t need = 8192 + 131072 + (size_t)4096 * 1024 * 8;  // tw + Wfs + X
  if (ws_size < need) {
    k_naive<<<4096, 256, 0, stream>>>(x, W, bs, vb, out);
    return;
  }
  f32x2* tw  = (f32x2*)d_ws;
  f32x2* Wfs = (f32x2*)((char*)d_ws + 8192);
  f32x2* X   = (f32x2*)((char*)d_ws + 8192 + 131072);

  k_twiddle<<<4, 256, 0, stream>>>(tw);
  // merged: blocks 0..3 -> 16 W-column spectra (scaled by (1/1024)*(2/ln2));
  // blocks 4..1027 -> 4096 x-row spectra + vb*rowsum into out
  k_fft_fwd<<<1028, 256, 0, stream>>>(W, x, tw, Wfs, X, vb, out);
  k_corr<<<4096, 256, 0, stream>>>(X, Wfs, bs, tw, out);
}

// Round 19
// 115.466 us; speedup vs baseline: 1.5751x; 1.0638x over previous
//
#include <hip/hip_runtime.h>
#include <hip/hip_bf16.h>
#include <math.h>

#define LN2F 0.6931471805599453f
#define SCL 9.765625e-4f       // 1/1024
#define TWO_OVER_LN2 2.885390081777927f

typedef __attribute__((ext_vector_type(2))) float f32x2;

// ---------------------------------------------------------------------------
// Circulant trick: y[b, j*1024+i] = sum_k x[b,k] W[(i+k)%1024, j] is circular
// cross-correlation -> y_row = IDFT( Wf_j * conj(X_b) ), length-1024.
// Order irrelevant under sum(logcosh): radix-4 DIF forward + adjoint radix-4
// DIT inverse, no bit reversal. 2 real outputs per complex IFFT.
// k_corr (r19): 1-WAVE blocks (64 thr), grid 16384 = 4096 b x 4 j-groups.
// Each wave owns TWO packed IFFT passes (j 4jg..4jg+3) phase-pipelined
// A0 A1 | B0 B1 | C0 C1 on disjoint padded LDS buffers -- identical per-wave
// code to r15/r18, but 17.4KB LDS/block -> 9 blocks/CU = 9 waves/CU
// (was 8 with 4-wave blocks), no __syncthreads, one atomicAdd per block.
// Padded LDS (phys = s + s>>4), base+imm addressing, conflict-free.
// Complex math = VOP3P inline asm (v_pk_mul/fma/add with op_sel/neg; no
// v_pk_max_f32 on gfx950). logcosh in log2 domain, one log2 per pair.
// 2/ln2 folded into Wfs scale + bias. Zero per-thread arrays (r7 lesson).
// ---------------------------------------------------------------------------

#define LSW(s) ((s) ^ (((s) >> 4) & 15))   // (fwd kernel LDS swizzle)

__device__ __forceinline__ f32x2 mk2(float x, float y) { f32x2 r; r.x = x; r.y = y; return r; }

// ---- VOP3P packed helpers (validated bit-exact through r14-r18) ----
__device__ __forceinline__ f32x2 pk_cmul(f32x2 a, f32x2 b) {   // a*b
  f32x2 d, t;
  asm("v_pk_mul_f32 %1, %2, %3 op_sel:[0,0] op_sel_hi:[0,1]\n\t"
      "v_pk_fma_f32 %0, %2, %3, %1 op_sel:[1,1,0] op_sel_hi:[1,0,1] neg_lo:[1,0,0]"
      : "=v"(d), "=&v"(t) : "v"(a), "v"(b));
  return d;
}
__device__ __forceinline__ f32x2 pk_cmulj(f32x2 a, f32x2 b) {  // a*conj(b)
  f32x2 d, t;
  asm("v_pk_mul_f32 %1, %2, %3 op_sel:[0,0] op_sel_hi:[0,1] neg_hi:[0,1]\n\t"
      "v_pk_fma_f32 %0, %2, %3, %1 op_sel:[1,1,0] op_sel_hi:[1,0,1]"
      : "=v"(d), "=&v"(t) : "v"(a), "v"(b));
  return d;
}
__device__ __forceinline__ f32x2 pk_add(f32x2 a, f32x2 b) {
  f32x2 o;
  asm("v_pk_add_f32 %0, %1, %2" : "=v"(o) : "v"(a), "v"(b));
  return o;
}
__device__ __forceinline__ f32x2 pk_sub(f32x2 a, f32x2 b) {
  f32x2 o;
  asm("v_pk_add_f32 %0, %1, %2 neg_lo:[0,1] neg_hi:[0,1]" : "=v"(o) : "v"(a), "v"(b));
  return o;
}
__device__ __forceinline__ f32x2 pk_addrot_p(f32x2 a, f32x2 d) {  // a + i*d
  f32x2 o;
  asm("v_pk_add_f32 %0, %1, %2 op_sel:[0,1] op_sel_hi:[1,0] neg_lo:[0,1]"
      : "=v"(o) : "v"(a), "v"(d));
  return o;
}
__device__ __forceinline__ f32x2 pk_addrot_m(f32x2 a, f32x2 d) {  // a - i*d
  f32x2 o;
  asm("v_pk_add_f32 %0, %1, %2 op_sel:[0,1] op_sel_hi:[1,0] neg_hi:[0,1]"
      : "=v"(o) : "v"(a), "v"(d));
  return o;
}
__device__ __forceinline__ f32x2 pk_nabs(f32x2 a) {  // |a| elementwise
  return mk2(fabsf(a.x), fabsf(a.y));
}

__device__ __forceinline__ float fast_exp2(float x) {
#if __has_builtin(__builtin_amdgcn_exp2f)
  return __builtin_amdgcn_exp2f(x);
#else
  return exp2f(x);
#endif
}
__device__ __forceinline__ float fast_log2(float x) {
#if __has_builtin(__builtin_amdgcn_logf)
  return __builtin_amdgcn_logf(x);
#else
  return __log2f(x);
#endif
}

// TWF[m] = e^{-2*pi*i*m/1024} for the compile-time m we need
__device__ __forceinline__ f32x2 Ctw(int m) {
  switch (m) {
    case 0:   return mk2(1.f, 0.f);
    case 1:   return mk2(0.999981175f, -0.006135885f);
    case 2:   return mk2(0.999924702f, -0.012271538f);
    case 3:   return mk2(0.999830582f, -0.018406730f);
    case 64:  return mk2(0.923879533f, -0.382683432f);
    case 128: return mk2(0.707106781f, -0.707106781f);
    case 192: return mk2(0.382683432f, -0.923879533f);
    case 256: return mk2(0.f, -1.f);
    case 384: return mk2(-0.707106781f, -0.707106781f);
    case 576: return mk2(-0.923879533f, 0.382683432f);
  }
  return mk2(1.f, 0.f);
}

// forward DIF butterfly (output twiddles, e^{-}) -- packed asm
// t3 = -i*d, so t2+t3 = t2 - i*d (addrot_m), t2-t3 = t2 + i*d (addrot_p)
#define BFLY_F(x0,x1,x2,x3,W1,W2,W3,y0,y1,y2,y3) do { \
  f32x2 t0 = pk_add(x0,x2), t1 = pk_add(x1,x3), t2 = pk_sub(x0,x2), d_ = pk_sub(x1,x3); \
  y0 = pk_add(t0,t1); y1 = pk_cmul(pk_addrot_m(t2,d_), W1); \
  y2 = pk_cmul(pk_sub(t0,t1), W2); y3 = pk_cmul(pk_addrot_p(t2,d_), W3); } while(0)

// inverse DIT butterfly (input conj-twiddles, e^{+}) -- packed asm
#define BFLY_I(x0,x1,x2,x3,W1,W2,W3,y0,y1,y2,y3) do { \
  f32x2 u1 = pk_cmulj(x1,W1), u2 = pk_cmulj(x2,W2), u3 = pk_cmulj(x3,W3); \
  f32x2 t0 = pk_add(x0,u2), t1 = pk_add(u1,u3), t2 = pk_sub(x0,u2), d_ = pk_sub(u1,u3); \
  y0 = pk_add(t0,t1); y1 = pk_addrot_p(t2,d_); \
  y2 = pk_sub(t0,t1); y3 = pk_addrot_m(t2,d_); } while(0)

#define BFLY_I1(x0,x1,x2,x3,y0,y1,y2,y3) do { \
  f32x2 t0 = pk_add(x0,x2), t1 = pk_add(x1,x3), t2 = pk_sub(x0,x2), d_ = pk_sub(x1,x3); \
  y0 = pk_add(t0,t1); y1 = pk_addrot_p(t2,d_); \
  y2 = pk_sub(t0,t1); y3 = pk_addrot_m(t2,d_); } while(0)

__global__ void k_twiddle(f32x2* __restrict__ tw) {
  int m = blockIdx.x * 256 + threadIdx.x;
  float th = (float)(2.0 * M_PI / 1024.0) * (float)m;
  tw[m] = mk2(cosf(th), -sinf(th));
}

// Merged forward FFT-1024 (radix-4 DIF, packed asm). One wave per row,
// 4 rows/block. Blocks 0..3: W columns -> Wfs (scaled); blocks 4..1027:
// x rows -> X (+ vb*rowsum into out).
__global__ __launch_bounds__(256, 3) void k_fft_fwd(
    const float* __restrict__ W, const float* __restrict__ x,
    const f32x2* __restrict__ tw, f32x2* __restrict__ Wfs, f32x2* __restrict__ X,
    const float* __restrict__ vbias, float* __restrict__ out) {
  __shared__ __align__(16) f32x2 fft[4][1024];
  int tid = threadIdx.x, wv = tid >> 6, u = tid & 63;
  int bb = blockIdx.x;
  int isw = (bb < 4);
  int row = (isw ? bb : bb - 4) * 4 + wv;
  const float* xr = isw ? (W + row) : (x + (size_t)row * 1024);
  int estride = isw ? 16 : 1;
  float scale = isw ? (SCL * TWO_OVER_LN2) : 1.0f;
  f32x2* drow = (isw ? Wfs : X) + (size_t)row * 1024;

  f32x2* L = fft[wv];
  f32x2 twu = tw[u];
  f32x2 tw4u = tw[4 * u];
  int tp = u & 3;
  f32x2 tw16t = tw[16 * tp], tw64t = tw[64 * tp];

  float vr[4][4]; float rs = 0.f;
  #pragma unroll
  for (int a = 0; a < 4; ++a)
    #pragma unroll
    for (int k = 0; k < 4; ++k) {
      float s = xr[(u + 64 * a + 256 * k) * estride];
      vr[a][k] = s; rs += s;
    }
  f32x2 v[4][4];
  #pragma unroll
  for (int a = 0; a < 4; ++a) {
    float x0 = vr[a][0], x1 = vr[a][1], x2 = vr[a][2], x3 = vr[a][3];
    float t0 = x0 + x2, t1 = x1 + x3, t2 = x0 - x2, dm = x1 - x3;
    f32x2 W1 = pk_cmul(twu, Ctw(64 * a));
    f32x2 W2 = pk_cmul(W1, W1), W3 = pk_cmul(W1, W2);
    v[a][0] = mk2(t0 + t1, 0.f);
    v[a][1] = pk_cmul(mk2(t2, -dm), W1);
    v[a][2] = pk_cmul(mk2(t0 - t1, 0.f), W2);
    v[a][3] = pk_cmul(mk2(t2, dm), W3);
  }
  {
    f32x2 W1 = tw4u, W2 = pk_cmul(W1, W1), W3 = pk_cmul(W1, W2);
    #pragma unroll
    for (int k = 0; k < 4; ++k) {
      f32x2 y0,y1,y2,y3;
      BFLY_F(v[0][k], v[1][k], v[2][k], v[3][k], W1, W2, W3, y0,y1,y2,y3);
      v[0][k]=y0; v[1][k]=y1; v[2][k]=y2; v[3][k]=y3;
    }
  }
  #pragma unroll
  for (int a = 0; a < 4; ++a)
    #pragma unroll
    for (int k = 0; k < 4; ++k)
      L[LSW(u + 64 * a + 256 * k)] = v[a][k];

  int D = u >> 2;
  f32x2 w[4][4];
  #pragma unroll
  for (int c = 0; c < 4; ++c)
    #pragma unroll
    for (int ap = 0; ap < 4; ++ap)
      w[c][ap] = L[LSW(64 * D + 16 * c + 4 * ap + tp)];
  #pragma unroll
  for (int ap = 0; ap < 4; ++ap) {
    f32x2 W1 = pk_cmul(Ctw(64 * ap), tw16t);
    f32x2 W2 = pk_cmul(W1, W1), W3 = pk_cmul(W1, W2);
    f32x2 y0,y1,y2,y3;
    BFLY_F(w[0][ap], w[1][ap], w[2][ap], w[3][ap], W1, W2, W3, y0,y1,y2,y3);
    w[0][ap]=y0; w[1][ap]=y1; w[2][ap]=y2; w[3][ap]=y3;
  }
  {
    f32x2 W1 = tw64t, W2 = pk_cmul(W1, W1), W3 = pk_cmul(W1, W2);
    #pragma unroll
    for (int c = 0; c < 4; ++c) {
      f32x2 y0,y1,y2,y3;
      BFLY_F(w[c][0], w[c][1], w[c][2], w[c][3], W1, W2, W3, y0,y1,y2,y3);
      w[c][0]=y0; w[c][1]=y1; w[c][2]=y2; w[c][3]=y3;
    }
  }
  #pragma unroll
  for (int c = 0; c < 4; ++c)
    #pragma unroll
    for (int ap = 0; ap < 4; ++ap)
      L[LSW(64 * D + 16 * c + 4 * ap + tp)] = w[c][ap];

  #pragma unroll
  for (int j = 0; j < 4; ++j) {
    f32x2 z0 = L[LSW(16 * u + 4 * j)];
    f32x2 z1 = L[LSW(16 * u + 4 * j + 1)];
    f32x2 z2 = L[LSW(16 * u + 4 * j + 2)];
    f32x2 z3 = L[LSW(16 * u + 4 * j + 3)];
    f32x2 t0 = pk_add(z0,z2), t1 = pk_add(z1,z3), t2 = pk_sub(z0,z2), d = pk_sub(z1,z3);
    f32x2 y0 = pk_add(t0,t1) * scale, y1 = pk_addrot_m(t2,d) * scale;
    f32x2 y2 = pk_sub(t0,t1) * scale, y3 = pk_addrot_p(t2,d) * scale;
    float4* dp = (float4*)(drow + 16 * u + 4 * j);
    dp[0] = make_float4(y0.x, y0.y, y1.x, y1.y);
    dp[1] = make_float4(y2.x, y2.y, y3.x, y3.y);
  }
  if (!isw) {
    #pragma unroll
    for (int m = 32; m; m >>= 1) rs += __shfl_down(rs, m);
    if (u == 0) out[row] = vbias[0] * rs;
  }
}

// ---- k_corr phase macros: padded LDS (phys = s + s>>4), packed-asm math ----

#define PW(M, XA, XB, ZA, ZB) do { \
  float4 qa = W0p[M], qb = W1p[M]; \
  f32x2 g1 = pk_cmulj(mk2(qa.x,qa.y), XA); \
  f32x2 g2 = pk_cmulj(mk2(qb.x,qb.y), XA); \
  ZA = pk_addrot_p(g1, g2); \
  g1 = pk_cmulj(mk2(qa.z,qa.w), XB); \
  g2 = pk_cmulj(mk2(qb.z,qb.w), XB); \
  ZB = pk_addrot_p(g1, g2); } while(0)

// phase A: pointwise + s0 + s1; store logical 16u+i at phys 17u+i (LPA = L+17u)
#define QP_A(P, LPA) do { \
  const float4* W0p = (const float4*)(Wfs + (size_t)(2*(P)) * 1024 + s16); \
  const float4* W1p = (const float4*)(Wfs + (size_t)(2*(P) + 1) * 1024 + s16); \
  f32x2 z0,z1,z2,z3,z4,z5,z6,z7,z8,z9,z10,z11,z12,z13,z14,z15; \
  PW(0, xr0, xr1, z0, z1);   PW(1, xr2, xr3, z2, z3); \
  PW(2, xr4, xr5, z4, z5);   PW(3, xr6, xr7, z6, z7); \
  PW(4, xr8, xr9, z8, z9);   PW(5, xr10, xr11, z10, z11); \
  PW(6, xr12, xr13, z12, z13); PW(7, xr14, xr15, z14, z15); \
  BFLY_I1(z0,z1,z2,z3, z0,z1,z2,z3); \
  BFLY_I1(z4,z5,z6,z7, z4,z5,z6,z7); \
  BFLY_I1(z8,z9,z10,z11, z8,z9,z10,z11); \
  BFLY_I1(z12,z13,z14,z15, z12,z13,z14,z15); \
  BFLY_I1(z0,z4,z8,z12, z0,z4,z8,z12); \
  BFLY_I(z1,z5,z9,z13, Ctw(64),Ctw(128),Ctw(192), z1,z5,z9,z13); \
  BFLY_I(z2,z6,z10,z14, Ctw(128),Ctw(256),Ctw(384), z2,z6,z10,z14); \
  BFLY_I(z3,z7,z11,z15, Ctw(192),Ctw(384),Ctw(576), z3,z7,z11,z15); \
  (LPA)[0]=z0;   (LPA)[1]=z1;   (LPA)[2]=z2;   (LPA)[3]=z3; \
  (LPA)[4]=z4;   (LPA)[5]=z5;   (LPA)[6]=z6;   (LPA)[7]=z7; \
  (LPA)[8]=z8;   (LPA)[9]=z9;   (LPA)[10]=z10; (LPA)[11]=z11; \
  (LPA)[12]=z12; (LPA)[13]=z13; (LPA)[14]=z14; (LPA)[15]=z15; \
} while(0)

// phase B: logical 256B'+64c+16a+t -> phys (272B'+t) + (68c+17a)
#define QP_B(LPB) do { \
  f32x2 w00,w01,w02,w03,w10,w11,w12,w13,w20,w21,w22,w23,w30,w31,w32,w33; \
  w00 = (LPB)[0];   w01 = (LPB)[68];  w02 = (LPB)[136]; w03 = (LPB)[204]; \
  w10 = (LPB)[17];  w11 = (LPB)[85];  w12 = (LPB)[153]; w13 = (LPB)[221]; \
  w20 = (LPB)[34];  w21 = (LPB)[102]; w22 = (LPB)[170]; w23 = (LPB)[238]; \
  w30 = (LPB)[51];  w31 = (LPB)[119]; w32 = (LPB)[187]; w33 = (LPB)[255]; \
  BFLY_I(w00,w10,w20,w30, TB1,TB2,TB3, w00,w10,w20,w30); \
  BFLY_I(w01,w11,w21,w31, TB1,TB2,TB3, w01,w11,w21,w31); \
  BFLY_I(w02,w12,w22,w32, TB1,TB2,TB3, w02,w12,w22,w32); \
  BFLY_I(w03,w13,w23,w33, TB1,TB2,TB3, w03,w13,w23,w33); \
  BFLY_I(w00,w01,w02,w03, TC10,TC20,TC30, w00,w01,w02,w03); \
  BFLY_I(w10,w11,w12,w13, TC11,TC21,TC31, w10,w11,w12,w13); \
  BFLY_I(w20,w21,w22,w23, TC12,TC22,TC32, w20,w21,w22,w23); \
  BFLY_I(w30,w31,w32,w33, TC13,TC23,TC33, w30,w31,w32,w33); \
  (LPB)[0]=w00;   (LPB)[68]=w01;  (LPB)[136]=w02; (LPB)[204]=w03; \
  (LPB)[17]=w10;  (LPB)[85]=w11;  (LPB)[153]=w12; (LPB)[221]=w13; \
  (LPB)[34]=w20;  (LPB)[102]=w21; (LPB)[170]=w22; (LPB)[238]=w23; \
  (LPB)[51]=w30;  (LPB)[119]=w31; (LPB)[187]=w32; (LPB)[255]=w33; \
} while(0)

// log2-domain logcosh: u already = |v+b|*2/ln2 (scale folded); one log2 per pair
#define LCACC(C, B2, ACC) do { \
  f32x2 t2_ = pk_add((C), (B2)); \
  f32x2 u2_ = pk_nabs(t2_); \
  float p_ = (1.f + fast_exp2(-u2_.x)) * (1.f + fast_exp2(-u2_.y)); \
  ACC += fast_log2(p_); \
  accU = pk_add(accU, u2_); } while(0)

// phase C: logical 4u+I+256k -> phys (4u+(u>>2)) + (I+272k)
#define QPC_PH(LPC, I, T1, T2, T3, B2) do { \
  f32x2 c0 = (LPC)[(I)],     c1 = (LPC)[(I)+272]; \
  f32x2 c2 = (LPC)[(I)+544], c3 = (LPC)[(I)+816]; \
  BFLY_I(c0,c1,c2,c3,T1,T2,T3,c0,c1,c2,c3); \
  LCACC(c0, B2, accL0); LCACC(c1, B2, accL1); \
  LCACC(c2, B2, accL0); LCACC(c3, B2, accL1); } while(0)

#define QP_C(LPC, B2) do { \
  QPC_PH(LPC, 0, TD10, TD20, TD30, B2); \
  QPC_PH(LPC, 1, TD11, TD21, TD31, B2); \
  QPC_PH(LPC, 2, TD12, TD22, TD32, B2); \
  QPC_PH(LPC, 3, TD13, TD23, TD33, B2); } while(0)

// 1-wave blocks: block = (b, jg), handles j 4jg..4jg+3 via two pipelined
// passes on disjoint padded LDS buffers. 17.4KB LDS -> 9 blocks/CU.
__global__ __launch_bounds__(64, 4) void k_corr(
    const f32x2* __restrict__ X, const f32x2* __restrict__ Wfs,
    const float* __restrict__ bs, const f32x2* __restrict__ tw,
    float* __restrict__ out) {
  __shared__ __align__(16) f32x2 LBW[2][1088];   // [pass][slot]
  int u = threadIdx.x;
  int bid = blockIdx.x;
  int b = bid >> 2, jg = bid & 3;
  f32x2* L0 = LBW[0];
  f32x2* L1 = LBW[1];
  f32x2* LPA0 = L0 + 17 * u;
  f32x2* LPA1 = L1 + 17 * u;
  f32x2* LPB0 = L0 + 272 * (u >> 4) + (u & 15);
  f32x2* LPB1 = L1 + 272 * (u >> 4) + (u & 15);
  f32x2* LPC0 = L0 + 4 * u + (u >> 2);
  f32x2* LPC1 = L1 + 4 * u + (u >> 2);
  f32x2 tw4u = tw[4 * u];
  int t = u & 15;
  f32x2 tw16t = tw[16 * t], tw4t = tw[4 * t];
  int s16 = 16 * u;

  f32x2 xr0,xr1,xr2,xr3,xr4,xr5,xr6,xr7,xr8,xr9,xr10,xr11,xr12,xr13,xr14,xr15;
  {
    const float4* Xp = (const float4*)(X + (size_t)b * 1024 + s16);
    float4 q;
    q = Xp[0]; xr0  = mk2(q.x,q.y); xr1  = mk2(q.z,q.w);
    q = Xp[1]; xr2  = mk2(q.x,q.y); xr3  = mk2(q.z,q.w);
    q = Xp[2]; xr4  = mk2(q.x,q.y); xr5  = mk2(q.z,q.w);
    q = Xp[3]; xr6  = mk2(q.x,q.y); xr7  = mk2(q.z,q.w);
    q = Xp[4]; xr8  = mk2(q.x,q.y); xr9  = mk2(q.z,q.w);
    q = Xp[5]; xr10 = mk2(q.x,q.y); xr11 = mk2(q.z,q.w);
    q = Xp[6]; xr12 = mk2(q.x,q.y); xr13 = mk2(q.z,q.w);
    q = Xp[7]; xr14 = mk2(q.x,q.y); xr15 = mk2(q.z,q.w);
  }
  f32x2 bias20 = mk2(bs[4*jg]   * TWO_OVER_LN2, bs[4*jg+1] * TWO_OVER_LN2);
  f32x2 bias21 = mk2(bs[4*jg+2] * TWO_OVER_LN2, bs[4*jg+3] * TWO_OVER_LN2);

  // phase A of both passes
  QP_A(2*jg,     LPA0);
  QP_A(2*jg + 1, LPA1);

  // s2/s3 twiddles (shared by both passes)
  f32x2 TB1 = tw16t, TB2 = pk_cmul(TB1,TB1), TB3 = pk_cmul(TB1,TB2);
  f32x2 TC10 = tw4t,                  TC20 = pk_cmul(TC10,TC10), TC30 = pk_cmul(TC10,TC20);
  f32x2 TC11 = pk_cmul(tw4t,Ctw(64)),  TC21 = pk_cmul(TC11,TC11), TC31 = pk_cmul(TC11,TC21);
  f32x2 TC12 = pk_cmul(tw4t,Ctw(128)), TC22 = pk_cmul(TC12,TC12), TC32 = pk_cmul(TC12,TC22);
  f32x2 TC13 = pk_cmul(tw4t,Ctw(192)), TC23 = pk_cmul(TC13,TC13), TC33 = pk_cmul(TC13,TC23);

  // phase B of both passes
  QP_B(LPB0);
  QP_B(LPB1);

  // s4 twiddles (shared)
  f32x2 TD10 = tw4u,                 TD20 = pk_cmul(TD10,TD10), TD30 = pk_cmul(TD10,TD20);
  f32x2 TD11 = pk_cmul(tw4u,Ctw(1)), TD21 = pk_cmul(TD11,TD11), TD31 = pk_cmul(TD11,TD21);
  f32x2 TD12 = pk_cmul(tw4u,Ctw(2)), TD22 = pk_cmul(TD12,TD12), TD32 = pk_cmul(TD12,TD22);
  f32x2 TD13 = pk_cmul(tw4u,Ctw(3)), TD23 = pk_cmul(TD13,TD13), TD33 = pk_cmul(TD13,TD23);

  // phase C of both passes (log2-domain logcosh)
  float accL0 = 0.f, accL1 = 0.f;
  f32x2 accU = mk2(0.f, 0.f);
  QP_C(LPC0, bias20);
  QP_C(LPC1, bias21);

  float acc = (accL0 + accL1) + 0.5f * (accU.x + accU.y);
  #pragma unroll
  for (int m = 32; m; m >>= 1) acc += __shfl_down(acc, m);
  if (u == 0) atomicAdd(out + b, LN2F * (acc - 4096.f));
}

// fallback if workspace is too small: correct but slow
__global__ void k_naive(const float* __restrict__ x, const float* __restrict__ W,
                        const float* __restrict__ bs, const float* __restrict__ vb,
                        float* __restrict__ out) {
  int b = blockIdx.x;
  __shared__ float xs[1024];
  __shared__ float red[256];
  int t = threadIdx.x;
  float xsum = 0.f;
  for (int i = t; i < 1024; i += 256) { float v = x[(size_t)b * 1024 + i]; xs[i] = v; xsum += v; }
  __syncthreads();
  float tot = vb[0] * xsum;
  for (int h = t; h < 16384; h += 256) {
    int j = h >> 10, kh = h & 1023;
    float a = bs[j];
    for (int i = 0; i < 1024; ++i) a += xs[i] * W[((i + kh) & 1023) * 16 + j];
    float ax = fabsf(a);
    tot += ax + __logf(1.f + __expf(-2.f * ax)) - LN2F;
  }
  red[t] = tot;
  __syncthreads();
  for (int s2 = 128; s2; s2 >>= 1) { if (t < s2) red[t] += red[t + s2]; __syncthreads(); }
  if (t == 0) out[b] = red[0];
}

extern "C" void kernel_launch(void* const* d_in, const int* in_sizes, int n_in,
                              void* d_out, int out_size, void* d_ws, size_t ws_size,
                              hipStream_t stream) {
  const float* x  = (const float*)d_in[0];   // [4096,1024]
  const float* W  = (const float*)d_in[1];   // [1024,16]
  const float* bs = (const float*)d_in[2];   // [16]
  const float* vb = (const float*)d_in[3];   // [1]
  float* out = (float*)d_out;                // [4096]

  size_t need = 8192 + 131072 + (size_t)4096 * 1024 * 8;  // tw + Wfs + X
  if (ws_size < need) {
    k_naive<<<4096, 256, 0, stream>>>(x, W, bs, vb, out);
    return;
  }
  f32x2* tw  = (f32x2*)d_ws;
  f32x2* Wfs = (f32x2*)((char*)d_ws + 8192);
  f32x2* X   = (f32x2*)((char*)d_ws + 8192 + 131072);

  k_twiddle<<<4, 256, 0, stream>>>(tw);
  // merged: blocks 0..3 -> 16 W-column spectra (scaled by (1/1024)*(2/ln2));
  // blocks 4..1027 -> 4096 x-row spectra + vb*rowsum into out
  k_fft_fwd<<<1028, 256, 0, stream>>>(W, x, tw, Wfs, X, vb, out);
  // 1-wave blocks: (b, j-group), 4 per b
  k_corr<<<16384, 64, 0, stream>>>(X, Wfs, bs, tw, out);
}